// Round 2
// baseline (579.196 us; speedup 1.0000x reference)
//
#include <hip/hip_runtime.h>
#include <hip/hip_bf16.h>
#include <math.h>

// Problem constants
#define BB 8
#define NN_ 128
#define DD 256
#define LL 64
#define EH 64
#define NG 3

// ---------------- helpers ----------------
__device__ __forceinline__ float blockReduceSum(float v, float* sRed) {
    int tid = threadIdx.x;
    __syncthreads();
    sRed[tid] = v;
    __syncthreads();
    for (int s = 128; s > 0; s >>= 1) {
        if (tid < s) sRed[tid] += sRed[tid + s];
        __syncthreads();
    }
    return sRed[0];
}

// ---------------- adj dtype probe: 0 = bool8, 1 = int32, 2 = float32 ----------------
__global__ __launch_bounds__(256) void k_detect(const unsigned char* __restrict__ adj,
                                                int* __restrict__ mode) {
    __shared__ int sOff, sBig;
    const int tid = threadIdx.x;
    if (tid == 0) { sOff = 0; sBig = 0; }
    __syncthreads();
    int off = 0, big = 0;
    #pragma unroll
    for (int k = 0; k < 4; ++k) {
        unsigned char v = adj[tid * 4 + k];
        if (v > 1) big = 1;
        if (k != 0 && v != 0) off = 1;
    }
    if (off) atomicOr(&sOff, 1);
    if (big) atomicOr(&sBig, 1);
    __syncthreads();
    if (tid == 0) mode[0] = sBig ? 2 : (sOff ? 0 : 1);
}

// ---------------- node projection: h = nf @ p_node_w + b ----------------
__global__ __launch_bounds__(256) void k_nodeproj(
    const float* __restrict__ nf, const float* __restrict__ w,
    const float* __restrict__ bias, float* __restrict__ h)
{
    const int row = blockIdx.x, tid = threadIdx.x;
    __shared__ float sF[11];
    if (tid < 11) sF[tid] = nf[(size_t)row * 11 + tid];
    __syncthreads();
    float a = bias[tid];
    #pragma unroll
    for (int f = 0; f < 11; ++f) a += sF[f] * w[f * DD + tid];
    h[(size_t)row * DD + tid] = a;
}

// ---------------- layer-cost encoder (conv1d + linear) ----------------
__global__ __launch_bounds__(256) void k_layer_enc(
    const float* __restrict__ lc, const float* __restrict__ cw,
    const float* __restrict__ cb, const float* __restrict__ lpw,
    const float* __restrict__ lpb, float* __restrict__ le)
{
    const int b = blockIdx.x, tid = threadIdx.x;
    __shared__ float sLe[992];
    for (int idx = tid; idx < 992; idx += 256) {
        int c = idx / 31, t = idx % 31;
        float a = cb[c];
        #pragma unroll
        for (int k = 0; k < 4; ++k) a += lc[b * LL + 2 * t + k] * cw[c * 4 + k];
        sLe[idx] = fmaxf(a, 0.f);
    }
    __syncthreads();
    float acc = lpb[tid];
    for (int k = 0; k < 992; ++k) acc += sLe[k] * lpw[k * DD + tid];
    le[b * DD + tid] = acc;
}

// ---------------- per-layer: preg = h @ gw1[:256] + gb1 (no relu yet) ----------------
__global__ __launch_bounds__(256) void k_pregate(
    const float* __restrict__ h, const float* __restrict__ gw1,
    const float* __restrict__ gb1, float* __restrict__ preg)
{
    const int tid = threadIdx.x;
    const int row0 = blockIdx.x * 4;
    const int r = tid >> 6, t = tid & 63;
    __shared__ float sH[4][DD];
    for (int idx = tid; idx < 4 * DD; idx += 256)
        sH[idx >> 8][idx & 255] = h[(size_t)row0 * DD + idx];
    __syncthreads();
    float a = gb1[t];
    for (int k = 0; k < DD; ++k) a += sH[r][k] * gw1[k * EH + t];
    preg[(size_t)(row0 + r) * EH + t] = a;
}

// ---------------- fused edge-gate + masked aggregation ----------------
// block = (b,i); thread d owns output channel d; gw2 column cached in regs.
#define JT 8
__global__ __launch_bounds__(256) void k_edge(
    const float* __restrict__ h, const float* __restrict__ preg,
    const float* __restrict__ edge, const void* __restrict__ adj,
    const int* __restrict__ mode,
    const float* __restrict__ gw1,   // layer base (259,64): rows 256..258 = edge part
    const float* __restrict__ gw2,   // (64,256)
    const float* __restrict__ gb2,   // (256)
    float* __restrict__ agg_mean, float* __restrict__ agg_max)
{
    const int tid = threadIdx.x;
    const int bi = blockIdx.x;              // b*N + i
    const int b = bi >> 7;
    const int md = mode[0];
    __shared__ float sWe[3][EH];
    __shared__ __align__(16) float sHid[JT][EH];
    if (tid < 3 * EH) sWe[tid / EH][tid % EH] = gw1[(DD + tid / EH) * EH + (tid % EH)];
    // register-cache gw2 column d = tid
    float w[EH];
    #pragma unroll
    for (int t = 0; t < EH; ++t) w[t] = gw2[t * DD + tid];
    const float bias = gb2[tid];
    const float* eB = edge + (size_t)bi * NN_ * 3;
    const unsigned char* aB8 = (const unsigned char*)adj + (size_t)bi * NN_;
    const int* aB32 = (const int*)adj + (size_t)bi * NN_;
    const float* aBf = (const float*)adj + (size_t)bi * NN_;
    const float* pB = preg + (size_t)b * NN_ * EH;
    const float* hB = h + (size_t)b * NN_ * DD;
    float vsum = 0.f, vmax = -INFINITY, cnt = 0.f;
    __syncthreads();
    for (int j0 = 0; j0 < NN_; j0 += JT) {
        // cooperative hidden tile: JT*64 values, 2 per thread
        #pragma unroll
        for (int q = 0; q < (JT * EH) / 256; ++q) {
            int idx = tid + q * 256;
            int jl = idx >> 6, t = idx & 63;
            int j = j0 + jl;
            float e0 = eB[j * 3 + 0], e1 = eB[j * 3 + 1], e2 = eB[j * 3 + 2];
            float v = pB[j * EH + t] + e0 * sWe[0][t] + e1 * sWe[1][t] + e2 * sWe[2][t];
            sHid[jl][t] = fmaxf(v, 0.f);
        }
        __syncthreads();
        #pragma unroll
        for (int jl = 0; jl < JT; ++jl) {
            int j = j0 + jl;
            int mv = (md == 1) ? aB32[j]
                   : (md == 2) ? (aBf[j] != 0.f)
                   : (int)aB8[j];
            if (!mv) continue;               // uniform branch: gate unused when masked
            float acc0 = bias, acc1 = 0.f;
            const float4* hv = (const float4*)sHid[jl];
            #pragma unroll
            for (int t4 = 0; t4 < EH / 8; ++t4) {
                float4 ha = hv[2 * t4], hb = hv[2 * t4 + 1];
                acc0 += ha.x * w[t4 * 8 + 0] + ha.y * w[t4 * 8 + 1] +
                        ha.z * w[t4 * 8 + 2] + ha.w * w[t4 * 8 + 3];
                acc1 += hb.x * w[t4 * 8 + 4] + hb.y * w[t4 * 8 + 5] +
                        hb.z * w[t4 * 8 + 6] + hb.w * w[t4 * 8 + 7];
            }
            float gate = 1.0f / (1.0f + __expf(-(acc0 + acc1)));
            float msg = gate * hB[j * DD + tid];
            vsum += msg;
            vmax = fmaxf(vmax, msg);
            cnt += 1.f;
        }
        __syncthreads();
    }
    agg_mean[(size_t)bi * DD + tid] = vsum / fmaxf(cnt, 1.f);
    agg_max[(size_t)bi * DD + tid] = (cnt > 0.f) ? vmax : 0.f;
}

// ---------------- update MLP + residual + layernorm (in-place on h) ----------------
__global__ __launch_bounds__(256) void k_update(
    const float* __restrict__ agg_mean, const float* __restrict__ agg_max,
    const float* __restrict__ uw1, const float* __restrict__ ub1,
    const float* __restrict__ uw2, const float* __restrict__ ub2,
    const float* __restrict__ lng, const float* __restrict__ lnb,
    float* __restrict__ h)
{
    const int tid = threadIdx.x;
    const int row0 = blockIdx.x * 4;
    __shared__ float sUi[4][3 * DD];
    __shared__ float sHid[4][DD];
    __shared__ float sRed[256];
    for (int idx = tid; idx < 4 * 3 * DD; idx += 256) {
        int r = idx / (3 * DD), k = idx % (3 * DD);
        int row = row0 + r;
        float v;
        if (k < DD)            v = h[(size_t)row * DD + k];
        else if (k < 2 * DD)   v = agg_mean[(size_t)row * DD + (k - DD)];
        else                   v = agg_max[(size_t)row * DD + (k - 2 * DD)];
        sUi[r][k] = v;
    }
    __syncthreads();
    float b1 = ub1[tid];
    float a0 = b1, a1 = b1, a2 = b1, a3 = b1;
    for (int k = 0; k < 3 * DD; ++k) {
        float wv = uw1[k * DD + tid];
        a0 += sUi[0][k] * wv; a1 += sUi[1][k] * wv;
        a2 += sUi[2][k] * wv; a3 += sUi[3][k] * wv;
    }
    sHid[0][tid] = fmaxf(a0, 0.f); sHid[1][tid] = fmaxf(a1, 0.f);
    sHid[2][tid] = fmaxf(a2, 0.f); sHid[3][tid] = fmaxf(a3, 0.f);
    __syncthreads();
    float b2 = ub2[tid];
    float x[4] = {b2, b2, b2, b2};
    for (int k = 0; k < DD; ++k) {
        float wv = uw2[k * DD + tid];
        x[0] += sHid[0][k] * wv; x[1] += sHid[1][k] * wv;
        x[2] += sHid[2][k] * wv; x[3] += sHid[3][k] * wv;
    }
    #pragma unroll
    for (int r = 0; r < 4; ++r) x[r] += h[(size_t)(row0 + r) * DD + tid];
    const float g = lng[tid], be = lnb[tid];
    for (int r = 0; r < 4; ++r) {
        float mu = blockReduceSum(x[r], sRed) * (1.f / DD);
        float dc = x[r] - mu;
        float var = blockReduceSum(dc * dc, sRed) * (1.f / DD);
        h[(size_t)(row0 + r) * DD + tid] = dc * rsqrtf(var + 1e-5f) * g + be;
    }
}

// ---------------- graph embed ----------------
__global__ __launch_bounds__(256) void k_gembed(
    const float* __restrict__ nf, const float* __restrict__ h, float* __restrict__ ge)
{
    const int b = blockIdx.x, tid = threadIdx.x;
    __shared__ float sW[NN_];
    __shared__ float sRed[256];
    if (tid < NN_) {
        const float* p = nf + ((size_t)b * NN_ + tid) * 11;
        sW[tid] = p[0] * p[7];
    }
    __syncthreads();
    float part = (tid < NN_) ? sW[tid] : 0.f;
    float wsum = blockReduceSum(part, sRed);
    float acc = 0.f;
    for (int n = 0; n < NN_; ++n) acc += sW[n] * h[((size_t)b * NN_ + n) * DD + tid];
    ge[b * DD + tid] = acc / fmaxf(wsum, 1e-8f);
}

// ---------------- head: query, stop_logit, value ----------------
__global__ __launch_bounds__(256) void k_head(
    const float* __restrict__ ge, const float* __restrict__ le,
    const float* __restrict__ gd,
    const float* __restrict__ qw, const float* __restrict__ qb,
    const float* __restrict__ sw1, const float* __restrict__ sb1,
    const float* __restrict__ sw2, const float* __restrict__ sb2,
    const float* __restrict__ vw1, const float* __restrict__ vb1,
    const float* __restrict__ vw2, const float* __restrict__ vb2,
    float* __restrict__ query, float* __restrict__ out)
{
    const int b = blockIdx.x, tid = threadIdx.x;
    __shared__ float sQi[514];
    __shared__ float sRed[256];
    sQi[tid] = ge[b * DD + tid];
    sQi[DD + tid] = le[b * DD + tid];
    if (tid < 2) sQi[2 * DD + tid] = gd[b * 2 + tid];
    __syncthreads();
    float aq = qb[tid];
    for (int k = 0; k < 514; ++k) aq += sQi[k] * qw[k * DD + tid];
    query[b * DD + tid] = aq;
    // stop head: si = [ge(256), gd(2)]
    float as = sb1[tid];
    for (int k = 0; k < DD; ++k) as += sQi[k] * sw1[k * DD + tid];
    as += sQi[512] * sw1[256 * DD + tid] + sQi[513] * sw1[257 * DD + tid];
    as = fmaxf(as, 0.f);
    float stop = blockReduceSum(as * sw2[tid], sRed);
    // value head
    float av = vb1[tid];
    for (int k = 0; k < 514; ++k) av += sQi[k] * vw1[k * DD + tid];
    av = fmaxf(av, 0.f);
    float val = blockReduceSum(av * vw2[tid], sRed);
    if (tid == 0) {
        out[b * 129 + 128] = stop + sb2[0];
        out[1032 + b] = val + vb2[0];
    }
}

// ---------------- device scores ----------------
__global__ __launch_bounds__(256) void k_scores(
    const float* __restrict__ h, const float* __restrict__ kw,
    const float* __restrict__ kb, const float* __restrict__ query,
    float* __restrict__ out)
{
    const int tid = threadIdx.x;
    const int row0 = blockIdx.x * 4;   // b*N + n
    __shared__ float sH[4][DD];
    __shared__ float sRed[256];
    for (int idx = tid; idx < 4 * DD; idx += 256)
        sH[idx >> 8][idx & 255] = h[(size_t)row0 * DD + idx];
    __syncthreads();
    float bb = kb[tid];
    float a0 = bb, a1 = bb, a2 = bb, a3 = bb;
    for (int k = 0; k < DD; ++k) {
        float wv = kw[k * DD + tid];
        a0 += sH[0][k] * wv; a1 += sH[1][k] * wv;
        a2 += sH[2][k] * wv; a3 += sH[3][k] * wv;
    }
    const int b = row0 >> 7;
    const float q = query[b * DD + tid];
    float s0 = blockReduceSum(a0 * q, sRed);
    float s1 = blockReduceSum(a1 * q, sRed);
    float s2 = blockReduceSum(a2 * q, sRed);
    float s3 = blockReduceSum(a3 * q, sRed);
    if (tid == 0) {
        int n0 = row0 & (NN_ - 1);
        out[b * 129 + n0 + 0] = s0 * 0.0625f;
        out[b * 129 + n0 + 1] = s1 * 0.0625f;
        out[b * 129 + n0 + 2] = s2 * 0.0625f;
        out[b * 129 + n0 + 3] = s3 * 0.0625f;
    }
}

// ---------------- copy h to output ----------------
__global__ void k_copy(const float* __restrict__ src, float* __restrict__ dst, int n) {
    int i = blockIdx.x * 256 + threadIdx.x;
    if (i < n) dst[i] = src[i];
}

extern "C" void kernel_launch(void* const* d_in, const int* in_sizes, int n_in,
                              void* d_out, int out_size, void* d_ws, size_t ws_size,
                              hipStream_t stream) {
    (void)in_sizes; (void)n_in; (void)out_size; (void)ws_size;
    const float* nf  = (const float*)d_in[0];
    const float* ef  = (const float*)d_in[1];
    const void*  adj = d_in[2];                 // dtype probed on device
    const float* lc  = (const float*)d_in[3];
    const float* gd  = (const float*)d_in[4];
    const float* pnw = (const float*)d_in[5];
    const float* pnb = (const float*)d_in[6];
    const float* gw1 = (const float*)d_in[7];
    const float* gb1 = (const float*)d_in[8];
    const float* gw2 = (const float*)d_in[9];
    const float* gb2 = (const float*)d_in[10];
    const float* uw1 = (const float*)d_in[11];
    const float* ub1 = (const float*)d_in[12];
    const float* uw2 = (const float*)d_in[13];
    const float* ub2 = (const float*)d_in[14];
    const float* lng = (const float*)d_in[15];
    const float* lnb = (const float*)d_in[16];
    const float* cw  = (const float*)d_in[17];
    const float* cb  = (const float*)d_in[18];
    const float* lpw = (const float*)d_in[19];
    const float* lpb = (const float*)d_in[20];
    const float* qw  = (const float*)d_in[21];
    const float* qb  = (const float*)d_in[22];
    const float* kw  = (const float*)d_in[23];
    const float* kb  = (const float*)d_in[24];
    const float* sw1 = (const float*)d_in[25];
    const float* sb1 = (const float*)d_in[26];
    const float* sw2 = (const float*)d_in[27];
    const float* sb2 = (const float*)d_in[28];
    const float* vw1 = (const float*)d_in[29];
    const float* vb1 = (const float*)d_in[30];
    const float* vw2 = (const float*)d_in[31];
    const float* vb2 = (const float*)d_in[32];

    float* ws = (float*)d_ws;                  // total 858113 floats = 3.44 MB
    float* h     = ws;                         // 262144
    float* preg  = ws + 262144;                // 65536
    float* amean = ws + 327680;                // 262144
    float* amax  = ws + 589824;                // 262144
    float* le    = ws + 851968;                // 2048
    float* ge    = ws + 854016;                // 2048
    float* query = ws + 856064;                // 2048
    int*   mode  = (int*)(ws + 858112);        // 1
    float* out   = (float*)d_out;

    k_detect<<<1, 256, 0, stream>>>((const unsigned char*)adj, mode);
    k_nodeproj<<<BB * NN_, 256, 0, stream>>>(nf, pnw, pnb, h);
    k_layer_enc<<<BB, 256, 0, stream>>>(lc, cw, cb, lpw, lpb, le);
    for (int i = 0; i < NG; ++i) {
        const float* gw1i = gw1 + (size_t)i * 259 * EH;
        k_pregate<<<BB * NN_ / 4, 256, 0, stream>>>(h, gw1i, gb1 + i * EH, preg);
        k_edge<<<BB * NN_, 256, 0, stream>>>(h, preg, ef, adj, mode, gw1i,
                                             gw2 + (size_t)i * EH * DD, gb2 + i * DD,
                                             amean, amax);
        k_update<<<BB * NN_ / 4, 256, 0, stream>>>(amean, amax,
                                                   uw1 + (size_t)i * 3 * DD * DD, ub1 + i * DD,
                                                   uw2 + (size_t)i * DD * DD, ub2 + i * DD,
                                                   lng + i * DD, lnb + i * DD, h);
    }
    k_gembed<<<BB, 256, 0, stream>>>(nf, h, ge);
    k_head<<<BB, 256, 0, stream>>>(ge, le, gd, qw, qb, sw1, sb1, sw2, sb2,
                                   vw1, vb1, vw2, vb2, query, out);
    k_scores<<<BB * NN_ / 4, 256, 0, stream>>>(h, kw, kb, query, out);
    k_copy<<<(BB * NN_ * DD + 255) / 256, 256, 0, stream>>>(h, out + 1040, BB * NN_ * DD);
}

// Round 3
// 513.657 us; speedup vs baseline: 1.1276x; 1.1276x over previous
//
#include <hip/hip_runtime.h>
#include <hip/hip_bf16.h>
#include <math.h>

// Problem constants
#define BB 8
#define NN_ 128
#define DD 256
#define LL 64
#define EH 64
#define NG 3

// ---------------- helpers ----------------
__device__ __forceinline__ float blockReduceSum(float v, float* sRed) {
    int tid = threadIdx.x;
    __syncthreads();
    sRed[tid] = v;
    __syncthreads();
    for (int s = 128; s > 0; s >>= 1) {
        if (tid < s) sRed[tid] += sRed[tid + s];
        __syncthreads();
    }
    return sRed[0];
}

// ---------------- adj dtype probe: 0 = bool8, 1 = int32, 2 = float32 ----------------
__global__ __launch_bounds__(256) void k_detect(const unsigned char* __restrict__ adj,
                                                int* __restrict__ mode) {
    __shared__ int sOff, sBig;
    const int tid = threadIdx.x;
    if (tid == 0) { sOff = 0; sBig = 0; }
    __syncthreads();
    int off = 0, big = 0;
    #pragma unroll
    for (int k = 0; k < 4; ++k) {
        unsigned char v = adj[tid * 4 + k];
        if (v > 1) big = 1;
        if (k != 0 && v != 0) off = 1;
    }
    if (off) atomicOr(&sOff, 1);
    if (big) atomicOr(&sBig, 1);
    __syncthreads();
    if (tid == 0) mode[0] = sBig ? 2 : (sOff ? 0 : 1);
}

// ---------------- node projection: h = nf @ p_node_w + b ----------------
__global__ __launch_bounds__(256) void k_nodeproj(
    const float* __restrict__ nf, const float* __restrict__ w,
    const float* __restrict__ bias, float* __restrict__ h)
{
    const int row = blockIdx.x, tid = threadIdx.x;
    __shared__ float sF[11];
    if (tid < 11) sF[tid] = nf[(size_t)row * 11 + tid];
    __syncthreads();
    float a = bias[tid];
    #pragma unroll
    for (int f = 0; f < 11; ++f) a += sF[f] * w[f * DD + tid];
    h[(size_t)row * DD + tid] = a;
}

// ---------------- layer-cost encoder: block = (b, 64-d chunk), split-k=4 ----------------
__global__ __launch_bounds__(256) void k_lenc(
    const float* __restrict__ lc, const float* __restrict__ cw,
    const float* __restrict__ cb, const float* __restrict__ lpw,
    const float* __restrict__ lpb, float* __restrict__ le)
{
    const int blk = blockIdx.x;
    const int b = blk >> 2, d0 = (blk & 3) * 64;
    const int tid = threadIdx.x;
    const int d = tid & 63, ks = tid >> 6;
    __shared__ float sLe[992];
    __shared__ float sC[LL];
    __shared__ float sP[4][64];
    if (tid < LL) sC[tid] = lc[b * LL + tid];
    __syncthreads();
    for (int idx = tid; idx < 992; idx += 256) {
        int c = idx / 31, t = idx % 31;
        float a = cb[c];
        #pragma unroll
        for (int k = 0; k < 4; ++k) a += sC[2 * t + k] * cw[c * 4 + k];
        sLe[idx] = fmaxf(a, 0.f);
    }
    __syncthreads();
    float acc = 0.f;
    for (int k = ks; k < 992; k += 4) acc += sLe[k] * lpw[(size_t)k * DD + d0 + d];
    sP[ks][d] = acc;
    __syncthreads();
    if (ks == 0)
        le[b * DD + d0 + d] = sP[0][d] + sP[1][d] + sP[2][d] + sP[3][d] + lpb[d0 + d];
}

// ---------------- per-layer: preg = h @ gw1[:256] + gb1 (no relu yet) ----------------
__global__ __launch_bounds__(256) void k_pregate(
    const float* __restrict__ h, const float* __restrict__ gw1,
    const float* __restrict__ gb1, float* __restrict__ preg)
{
    const int tid = threadIdx.x;
    const int row0 = blockIdx.x * 4;
    const int r = tid >> 6, t = tid & 63;
    __shared__ float sH[4][DD];
    for (int idx = tid; idx < 4 * DD; idx += 256)
        sH[idx >> 8][idx & 255] = h[(size_t)row0 * DD + idx];
    __syncthreads();
    float a = gb1[t];
    for (int k = 0; k < DD; ++k) a += sH[r][k] * gw1[k * EH + t];
    preg[(size_t)(row0 + r) * EH + t] = a;
}

// ---------------- fused edge-gate + masked aggregation ----------------
#define JT 8
__global__ __launch_bounds__(256) void k_edge(
    const float* __restrict__ h, const float* __restrict__ preg,
    const float* __restrict__ edge, const void* __restrict__ adj,
    const int* __restrict__ mode,
    const float* __restrict__ gw1,   // layer base (259,64): rows 256..258 = edge part
    const float* __restrict__ gw2,   // (64,256)
    const float* __restrict__ gb2,   // (256)
    float* __restrict__ agg_mean, float* __restrict__ agg_max)
{
    const int tid = threadIdx.x;
    const int bi = blockIdx.x;              // b*N + i
    const int b = bi >> 7;
    const int md = mode[0];
    __shared__ float sWe[3][EH];
    __shared__ __align__(16) float sHid[JT][EH];
    if (tid < 3 * EH) sWe[tid / EH][tid % EH] = gw1[(DD + tid / EH) * EH + (tid % EH)];
    float w[EH];
    #pragma unroll
    for (int t = 0; t < EH; ++t) w[t] = gw2[t * DD + tid];
    const float bias = gb2[tid];
    const float* eB = edge + (size_t)bi * NN_ * 3;
    const unsigned char* aB8 = (const unsigned char*)adj + (size_t)bi * NN_;
    const int* aB32 = (const int*)adj + (size_t)bi * NN_;
    const float* aBf = (const float*)adj + (size_t)bi * NN_;
    const float* pB = preg + (size_t)b * NN_ * EH;
    const float* hB = h + (size_t)b * NN_ * DD;
    float vsum = 0.f, vmax = -INFINITY, cnt = 0.f;
    __syncthreads();
    for (int j0 = 0; j0 < NN_; j0 += JT) {
        #pragma unroll
        for (int q = 0; q < (JT * EH) / 256; ++q) {
            int idx = tid + q * 256;
            int jl = idx >> 6, t = idx & 63;
            int j = j0 + jl;
            float e0 = eB[j * 3 + 0], e1 = eB[j * 3 + 1], e2 = eB[j * 3 + 2];
            float v = pB[j * EH + t] + e0 * sWe[0][t] + e1 * sWe[1][t] + e2 * sWe[2][t];
            sHid[jl][t] = fmaxf(v, 0.f);
        }
        __syncthreads();
        #pragma unroll
        for (int jl = 0; jl < JT; ++jl) {
            int j = j0 + jl;
            int mv = (md == 1) ? aB32[j]
                   : (md == 2) ? (aBf[j] != 0.f)
                   : (int)aB8[j];
            if (!mv) continue;               // uniform branch: gate unused when masked
            float acc0 = bias, acc1 = 0.f;
            const float4* hv = (const float4*)sHid[jl];
            #pragma unroll
            for (int t4 = 0; t4 < EH / 8; ++t4) {
                float4 ha = hv[2 * t4], hb = hv[2 * t4 + 1];
                acc0 += ha.x * w[t4 * 8 + 0] + ha.y * w[t4 * 8 + 1] +
                        ha.z * w[t4 * 8 + 2] + ha.w * w[t4 * 8 + 3];
                acc1 += hb.x * w[t4 * 8 + 4] + hb.y * w[t4 * 8 + 5] +
                        hb.z * w[t4 * 8 + 6] + hb.w * w[t4 * 8 + 7];
            }
            float gate = 1.0f / (1.0f + __expf(-(acc0 + acc1)));
            float msg = gate * hB[j * DD + tid];
            vsum += msg;
            vmax = fmaxf(vmax, msg);
            cnt += 1.f;
        }
        __syncthreads();
    }
    agg_mean[(size_t)bi * DD + tid] = vsum / fmaxf(cnt, 1.f);
    agg_max[(size_t)bi * DD + tid] = (cnt > 0.f) ? vmax : 0.f;
}

// ---------------- update MLP + residual + layernorm (in-place on h) ----------------
__global__ __launch_bounds__(256) void k_update(
    const float* __restrict__ agg_mean, const float* __restrict__ agg_max,
    const float* __restrict__ uw1, const float* __restrict__ ub1,
    const float* __restrict__ uw2, const float* __restrict__ ub2,
    const float* __restrict__ lng, const float* __restrict__ lnb,
    float* __restrict__ h, float* __restrict__ out2)
{
    const int tid = threadIdx.x;
    const int row0 = blockIdx.x * 4;
    __shared__ float sUi[4][3 * DD];
    __shared__ float sHid[4][DD];
    __shared__ float sRed[256];
    for (int idx = tid; idx < 4 * 3 * DD; idx += 256) {
        int r = idx / (3 * DD), k = idx % (3 * DD);
        int row = row0 + r;
        float v;
        if (k < DD)            v = h[(size_t)row * DD + k];
        else if (k < 2 * DD)   v = agg_mean[(size_t)row * DD + (k - DD)];
        else                   v = agg_max[(size_t)row * DD + (k - 2 * DD)];
        sUi[r][k] = v;
    }
    __syncthreads();
    float b1 = ub1[tid];
    float a0 = b1, a1 = b1, a2 = b1, a3 = b1;
    for (int k = 0; k < 3 * DD; ++k) {
        float wv = uw1[k * DD + tid];
        a0 += sUi[0][k] * wv; a1 += sUi[1][k] * wv;
        a2 += sUi[2][k] * wv; a3 += sUi[3][k] * wv;
    }
    sHid[0][tid] = fmaxf(a0, 0.f); sHid[1][tid] = fmaxf(a1, 0.f);
    sHid[2][tid] = fmaxf(a2, 0.f); sHid[3][tid] = fmaxf(a3, 0.f);
    __syncthreads();
    float b2 = ub2[tid];
    float x[4] = {b2, b2, b2, b2};
    for (int k = 0; k < DD; ++k) {
        float wv = uw2[k * DD + tid];
        x[0] += sHid[0][k] * wv; x[1] += sHid[1][k] * wv;
        x[2] += sHid[2][k] * wv; x[3] += sHid[3][k] * wv;
    }
    #pragma unroll
    for (int r = 0; r < 4; ++r) x[r] += h[(size_t)(row0 + r) * DD + tid];
    const float g = lng[tid], be = lnb[tid];
    for (int r = 0; r < 4; ++r) {
        float mu = blockReduceSum(x[r], sRed) * (1.f / DD);
        float dc = x[r] - mu;
        float var = blockReduceSum(dc * dc, sRed) * (1.f / DD);
        float res = dc * rsqrtf(var + 1e-5f) * g + be;
        h[(size_t)(row0 + r) * DD + tid] = res;
        if (out2) out2[(size_t)(row0 + r) * DD + tid] = res;
    }
}

// ---------------- graph embed ----------------
__global__ __launch_bounds__(256) void k_gembed(
    const float* __restrict__ nf, const float* __restrict__ h, float* __restrict__ ge)
{
    const int b = blockIdx.x, tid = threadIdx.x;
    __shared__ float sW[NN_];
    __shared__ float sRed[256];
    if (tid < NN_) {
        const float* p = nf + ((size_t)b * NN_ + tid) * 11;
        sW[tid] = p[0] * p[7];
    }
    __syncthreads();
    float part = (tid < NN_) ? sW[tid] : 0.f;
    float wsum = blockReduceSum(part, sRed);
    float acc = 0.f;
    for (int n = 0; n < NN_; ++n) acc += sW[n] * h[((size_t)b * NN_ + n) * DD + tid];
    ge[b * DD + tid] = acc / fmaxf(wsum, 1e-8f);
}

// ---------------- head stage 1: stacked GEMMs {query, stop-hidden, value-hidden} ----------------
// block = b*12 + c; c in [0,12): m = c>>2 (0=q,1=s,2=v), d-chunk = (c&3)*64
__global__ __launch_bounds__(256) void k_head_mm(
    const float* __restrict__ ge, const float* __restrict__ le,
    const float* __restrict__ gd,
    const float* __restrict__ qw, const float* __restrict__ qb,
    const float* __restrict__ sw1, const float* __restrict__ sb1,
    const float* __restrict__ vw1, const float* __restrict__ vb1,
    float* __restrict__ query, float* __restrict__ sh, float* __restrict__ vh)
{
    const int blk = blockIdx.x;
    const int b = blk / 12, c = blk % 12;
    const int m = c >> 2, d0 = (c & 3) * 64;
    const int tid = threadIdx.x;
    const int d = tid & 63, ks = tid >> 6;
    __shared__ float sX[514];
    __shared__ float sP[4][64];
    if (m == 1) {
        sX[tid] = ge[b * DD + tid];
        if (tid < 2) sX[DD + tid] = gd[b * 2 + tid];
    } else {
        sX[tid] = ge[b * DD + tid];
        sX[DD + tid] = le[b * DD + tid];
        if (tid < 2) sX[2 * DD + tid] = gd[b * 2 + tid];
    }
    __syncthreads();
    const int K = (m == 1) ? 258 : 514;
    const float* W = (m == 0) ? qw : (m == 1) ? sw1 : vw1;
    float acc = 0.f;
    for (int k = ks; k < K; k += 4) acc += sX[k] * W[(size_t)k * DD + d0 + d];
    sP[ks][d] = acc;
    __syncthreads();
    if (ks == 0) {
        float a = sP[0][d] + sP[1][d] + sP[2][d] + sP[3][d];
        int od = d0 + d;
        if (m == 0)      query[b * DD + od] = a + qb[od];
        else if (m == 1) sh[b * DD + od] = fmaxf(a + sb1[od], 0.f);
        else             vh[b * DD + od] = fmaxf(a + vb1[od], 0.f);
    }
}

// ---------------- head stage 2: stop / value reductions ----------------
__global__ __launch_bounds__(256) void k_head_fin(
    const float* __restrict__ sh, const float* __restrict__ vh,
    const float* __restrict__ sw2, const float* __restrict__ sb2,
    const float* __restrict__ vw2, const float* __restrict__ vb2,
    float* __restrict__ out)
{
    const int b = blockIdx.x, tid = threadIdx.x;
    __shared__ float sRed[256];
    float stop = blockReduceSum(sh[b * DD + tid] * sw2[tid], sRed);
    float val  = blockReduceSum(vh[b * DD + tid] * vw2[tid], sRed);
    if (tid == 0) {
        out[b * 129 + 128] = stop + sb2[0];
        out[1032 + b] = val + vb2[0];
    }
}

// ---------------- device scores ----------------
__global__ __launch_bounds__(256) void k_scores(
    const float* __restrict__ h, const float* __restrict__ kw,
    const float* __restrict__ kb, const float* __restrict__ query,
    float* __restrict__ out)
{
    const int tid = threadIdx.x;
    const int row0 = blockIdx.x * 4;   // b*N + n
    __shared__ float sH[4][DD];
    __shared__ float sRed[256];
    for (int idx = tid; idx < 4 * DD; idx += 256)
        sH[idx >> 8][idx & 255] = h[(size_t)row0 * DD + idx];
    __syncthreads();
    float bb = kb[tid];
    float a0 = bb, a1 = bb, a2 = bb, a3 = bb;
    for (int k = 0; k < DD; ++k) {
        float wv = kw[k * DD + tid];
        a0 += sH[0][k] * wv; a1 += sH[1][k] * wv;
        a2 += sH[2][k] * wv; a3 += sH[3][k] * wv;
    }
    const int b = row0 >> 7;
    const float q = query[b * DD + tid];
    float s0 = blockReduceSum(a0 * q, sRed);
    float s1 = blockReduceSum(a1 * q, sRed);
    float s2 = blockReduceSum(a2 * q, sRed);
    float s3 = blockReduceSum(a3 * q, sRed);
    if (tid == 0) {
        int n0 = row0 & (NN_ - 1);
        out[b * 129 + n0 + 0] = s0 * 0.0625f;
        out[b * 129 + n0 + 1] = s1 * 0.0625f;
        out[b * 129 + n0 + 2] = s2 * 0.0625f;
        out[b * 129 + n0 + 3] = s3 * 0.0625f;
    }
}

extern "C" void kernel_launch(void* const* d_in, const int* in_sizes, int n_in,
                              void* d_out, int out_size, void* d_ws, size_t ws_size,
                              hipStream_t stream) {
    (void)in_sizes; (void)n_in; (void)out_size; (void)ws_size;
    const float* nf  = (const float*)d_in[0];
    const float* ef  = (const float*)d_in[1];
    const void*  adj = d_in[2];                 // dtype probed on device
    const float* lc  = (const float*)d_in[3];
    const float* gd  = (const float*)d_in[4];
    const float* pnw = (const float*)d_in[5];
    const float* pnb = (const float*)d_in[6];
    const float* gw1 = (const float*)d_in[7];
    const float* gb1 = (const float*)d_in[8];
    const float* gw2 = (const float*)d_in[9];
    const float* gb2 = (const float*)d_in[10];
    const float* uw1 = (const float*)d_in[11];
    const float* ub1 = (const float*)d_in[12];
    const float* uw2 = (const float*)d_in[13];
    const float* ub2 = (const float*)d_in[14];
    const float* lng = (const float*)d_in[15];
    const float* lnb = (const float*)d_in[16];
    const float* cw  = (const float*)d_in[17];
    const float* cb  = (const float*)d_in[18];
    const float* lpw = (const float*)d_in[19];
    const float* lpb = (const float*)d_in[20];
    const float* qw  = (const float*)d_in[21];
    const float* qb  = (const float*)d_in[22];
    const float* kw  = (const float*)d_in[23];
    const float* kb  = (const float*)d_in[24];
    const float* sw1 = (const float*)d_in[25];
    const float* sb1 = (const float*)d_in[26];
    const float* sw2 = (const float*)d_in[27];
    const float* sb2 = (const float*)d_in[28];
    const float* vw1 = (const float*)d_in[29];
    const float* vb1 = (const float*)d_in[30];
    const float* vw2 = (const float*)d_in[31];
    const float* vb2 = (const float*)d_in[32];

    float* ws = (float*)d_ws;
    float* h     = ws;                         // 262144
    float* preg  = ws + 262144;                // 65536
    float* amean = ws + 327680;                // 262144
    float* amax  = ws + 589824;                // 262144
    float* le    = ws + 851968;                // 2048
    float* ge    = ws + 854016;                // 2048
    float* query = ws + 856064;                // 2048
    float* sh    = ws + 858112;                // 2048
    float* vh    = ws + 860160;                // 2048
    int*   mode  = (int*)(ws + 862208);        // 1
    float* out   = (float*)d_out;

    k_detect<<<1, 256, 0, stream>>>((const unsigned char*)adj, mode);
    k_nodeproj<<<BB * NN_, 256, 0, stream>>>(nf, pnw, pnb, h);
    k_lenc<<<BB * 4, 256, 0, stream>>>(lc, cw, cb, lpw, lpb, le);
    for (int i = 0; i < NG; ++i) {
        const float* gw1i = gw1 + (size_t)i * 259 * EH;
        k_pregate<<<BB * NN_ / 4, 256, 0, stream>>>(h, gw1i, gb1 + i * EH, preg);
        k_edge<<<BB * NN_, 256, 0, stream>>>(h, preg, ef, adj, mode, gw1i,
                                             gw2 + (size_t)i * EH * DD, gb2 + i * DD,
                                             amean, amax);
        k_update<<<BB * NN_ / 4, 256, 0, stream>>>(amean, amax,
                                                   uw1 + (size_t)i * 3 * DD * DD, ub1 + i * DD,
                                                   uw2 + (size_t)i * DD * DD, ub2 + i * DD,
                                                   lng + i * DD, lnb + i * DD, h,
                                                   (i == NG - 1) ? (out + 1040) : (float*)nullptr);
    }
    k_gembed<<<BB, 256, 0, stream>>>(nf, h, ge);
    k_head_mm<<<BB * 12, 256, 0, stream>>>(ge, le, gd, qw, qb, sw1, sb1, vw1, vb1,
                                           query, sh, vh);
    k_head_fin<<<BB, 256, 0, stream>>>(sh, vh, sw2, sb2, vw2, vb2, out);
    k_scores<<<BB * NN_ / 4, 256, 0, stream>>>(h, kw, kb, query, out);
}

// Round 4
// 348.096 us; speedup vs baseline: 1.6639x; 1.4756x over previous
//
#include <hip/hip_runtime.h>
#include <hip/hip_bf16.h>
#include <math.h>

// Problem constants
#define BB 8
#define NN_ 128
#define DD 256
#define LL 64
#define EH 64
#define NG 3

typedef __attribute__((ext_vector_type(8))) short bs8;   // 8 bf16 (4 VGPR)
typedef __attribute__((ext_vector_type(4))) float f4;    // 4 f32

__device__ __forceinline__ short f2bf(float f) {
    __hip_bfloat16 h = __float2bfloat16(f);
    return *reinterpret_cast<short*>(&h);
}

// ---------------- helpers ----------------
__device__ __forceinline__ float blockReduceSum(float v, float* sRed) {
    int tid = threadIdx.x;
    __syncthreads();
    sRed[tid] = v;
    __syncthreads();
    for (int s = 128; s > 0; s >>= 1) {
        if (tid < s) sRed[tid] += sRed[tid + s];
        __syncthreads();
    }
    return sRed[0];
}

// ---------------- adj dtype probe: 0 = bool8, 1 = int32, 2 = float32 ----------------
__global__ __launch_bounds__(256) void k_detect(const unsigned char* __restrict__ adj,
                                                int* __restrict__ mode) {
    __shared__ int sOff, sBig;
    const int tid = threadIdx.x;
    if (tid == 0) { sOff = 0; sBig = 0; }
    __syncthreads();
    int off = 0, big = 0;
    #pragma unroll
    for (int k = 0; k < 4; ++k) {
        unsigned char v = adj[tid * 4 + k];
        if (v > 1) big = 1;
        if (k != 0 && v != 0) off = 1;
    }
    if (off) atomicOr(&sOff, 1);
    if (big) atomicOr(&sBig, 1);
    __syncthreads();
    if (tid == 0) mode[0] = sBig ? 2 : (sOff ? 0 : 1);
}

// ---------------- node projection: h = nf @ p_node_w + b ----------------
__global__ __launch_bounds__(256) void k_nodeproj(
    const float* __restrict__ nf, const float* __restrict__ w,
    const float* __restrict__ bias, float* __restrict__ h)
{
    const int row = blockIdx.x, tid = threadIdx.x;
    __shared__ float sF[11];
    if (tid < 11) sF[tid] = nf[(size_t)row * 11 + tid];
    __syncthreads();
    float a = bias[tid];
    #pragma unroll
    for (int f = 0; f < 11; ++f) a += sF[f] * w[f * DD + tid];
    h[(size_t)row * DD + tid] = a;
}

// ---------------- layer-cost encoder stage A: conv1d + relu ----------------
__global__ __launch_bounds__(256) void k_conv(
    const float* __restrict__ lc, const float* __restrict__ cw,
    const float* __restrict__ cb, float* __restrict__ conv)
{
    const int b = blockIdx.x, tid = threadIdx.x;
    __shared__ float sC[LL];
    if (tid < LL) sC[tid] = lc[b * LL + tid];
    __syncthreads();
    for (int idx = tid; idx < 992; idx += 256) {
        int c = idx / 31, t = idx % 31;
        float a = cb[c];
        #pragma unroll
        for (int k = 0; k < 4; ++k) a += sC[2 * t + k] * cw[c * 4 + k];
        conv[b * 992 + idx] = fmaxf(a, 0.f);
    }
}

// ---------------- stage B: split-k GEMM [8x992]@[992x256] -> partials ----------------
// block = b(3b)|kseg(3b)|c4(2b): 256 blocks
__global__ __launch_bounds__(256) void k_lmm(
    const float* __restrict__ conv, const float* __restrict__ lpw,
    float* __restrict__ part)
{
    const int blk = blockIdx.x;
    const int b = blk >> 5, kseg = (blk >> 2) & 7, c4 = blk & 3;
    const int tid = threadIdx.x;
    const int d = tid & 63, ss = tid >> 6;
    __shared__ float sV[124];
    __shared__ float sP[4][64];
    if (tid < 124) sV[tid] = conv[b * 992 + kseg * 124 + tid];
    __syncthreads();
    float acc = 0.f;
    for (int k = ss; k < 124; k += 4)
        acc += sV[k] * lpw[(size_t)(kseg * 124 + k) * DD + c4 * 64 + d];
    sP[ss][d] = acc;
    __syncthreads();
    if (ss == 0)
        part[(b * 32 + kseg * 4 + c4) * 64 + d] = sP[0][d] + sP[1][d] + sP[2][d] + sP[3][d];
}

// ---------------- stage C: reduce partials + bias ----------------
__global__ __launch_bounds__(256) void k_lred(
    const float* __restrict__ part, const float* __restrict__ lpb,
    float* __restrict__ le)
{
    const int b = blockIdx.x, tid = threadIdx.x;
    const int c4 = tid >> 6, d = tid & 63;
    float a = lpb[tid];
    #pragma unroll
    for (int kseg = 0; kseg < 8; ++kseg)
        a += part[(b * 32 + kseg * 4 + c4) * 64 + d];
    le[b * DD + tid] = a;
}

// ---------------- per-layer: preg = h @ gw1[:256] + gb1 (no relu yet) ----------------
__global__ __launch_bounds__(256) void k_pregate(
    const float* __restrict__ h, const float* __restrict__ gw1,
    const float* __restrict__ gb1, float* __restrict__ preg)
{
    const int tid = threadIdx.x;
    const int row0 = blockIdx.x * 4;
    const int r = tid >> 6, t = tid & 63;
    __shared__ float sH[4][DD];
    for (int idx = tid; idx < 4 * DD; idx += 256)
        sH[idx >> 8][idx & 255] = h[(size_t)row0 * DD + idx];
    __syncthreads();
    float a = gb1[t];
    for (int k = 0; k < DD; ++k) a += sH[r][k] * gw1[k * EH + t];
    preg[(size_t)(row0 + r) * EH + t] = a;
}

// ---------------- fused edge-gate (MFMA) + masked aggregation ----------------
// block = (b,i), 4 waves. Wave w owns d-chunk [w*64, w*64+64).
// GEMM per block: hid[128j x 64k](bf16, LDS swz) @ gw2[64k x 256d](bf16, LDS swz^T)
__global__ __launch_bounds__(256) void k_edge(
    const float* __restrict__ h, const float* __restrict__ preg,
    const float* __restrict__ edge, const void* __restrict__ adj,
    const int* __restrict__ mode,
    const float* __restrict__ gw1,   // layer base (259,64): rows 256..258 = edge part
    const float* __restrict__ gw2,   // (64,256)
    const float* __restrict__ gb2,   // (256)
    float* __restrict__ agg_mean, float* __restrict__ agg_max)
{
    const int tid = threadIdx.x;
    const int bi = blockIdx.x;              // b*N + i
    const int b = bi >> 7;
    const int lane = tid & 63, w = tid >> 6;
    const int lrow = lane >> 4, lcol = lane & 15;
    const int md = mode[0];

    __shared__ __align__(16) unsigned int sHid[4096];     // bf16[128][64] pairs, swz
    __shared__ __align__(16) unsigned short sB[16384];    // bf16 [256d][64k], swz
    __shared__ float sWe[192];
    __shared__ float sE[384];
    __shared__ unsigned long long sMask[2];

    // ---- phase 0: We, edge feats, adjacency ballot ----
    if (tid < 192) sWe[tid] = gw1[16384 + tid];           // rows 256..258 contiguous
    const float* eB = edge + (size_t)bi * 384;
    for (int idx = tid; idx < 384; idx += 256) sE[idx] = eB[idx];
    if (tid < 128) {
        int mv;
        if (md == 1)      mv = ((const int*)adj)[(size_t)bi * NN_ + tid] != 0;
        else if (md == 2) mv = ((const float*)adj)[(size_t)bi * NN_ + tid] != 0.f;
        else              mv = ((const unsigned char*)adj)[(size_t)bi * NN_ + tid] != 0;
        unsigned long long bal = __ballot(mv);
        if ((tid & 63) == 0) sMask[tid >> 6] = bal;
    }
    __syncthreads();

    // ---- phase 1: hid = relu(preg + e.We) -> bf16 LDS; stage gw2 -> bf16 LDS^T ----
    const float* pB = preg + (size_t)b * NN_ * EH;
    #pragma unroll
    for (int q = 0; q < 16; ++q) {
        int idx = q * 256 + tid;
        int j = idx >> 5, p = idx & 31;
        float2 pv = *(const float2*)(pB + j * EH + 2 * p);
        float e0 = sE[j * 3], e1 = sE[j * 3 + 1], e2 = sE[j * 3 + 2];
        int t0 = 2 * p, t1 = t0 + 1;
        float v0 = fmaxf(pv.x + e0 * sWe[t0] + e1 * sWe[64 + t0] + e2 * sWe[128 + t0], 0.f);
        float v1 = fmaxf(pv.y + e0 * sWe[t1] + e1 * sWe[64 + t1] + e2 * sWe[128 + t1], 0.f);
        unsigned int pk = (unsigned int)(unsigned short)f2bf(v0) |
                          ((unsigned int)(unsigned short)f2bf(v1) << 16);
        sHid[j * 32 + (p ^ ((j & 7) << 2))] = pk;
    }
    #pragma unroll
    for (int q = 0; q < 64; ++q) {
        int idx = q * 256 + tid;                 // = k*256 + d
        int k = idx >> 8, d = idx & 255;
        sB[(d * 64 + k) ^ ((d & 7) << 3)] = (unsigned short)f2bf(gw2[idx]);
    }
    __syncthreads();

    const unsigned long long m0 = sMask[0], m1 = sMask[1];
    const float cntf = (float)(__popcll(m0) + __popcll(m1));

    // ---- B fragments + gate bias (per wave: 4 n-tiles x 2 k-steps) ----
    bs8 bfr[4][2];
    float bg[4];
    #pragma unroll
    for (int nt = 0; nt < 4; ++nt) {
        int d = w * 64 + nt * 16 + lcol;
        bg[nt] = gb2[d];
        #pragma unroll
        for (int ks = 0; ks < 2; ++ks) {
            int k0 = ks * 32 + lrow * 8;
            bfr[nt][ks] = *(const bs8*)(sB + ((d * 64 + k0) ^ ((d & 7) << 3)));
        }
    }

    const float* hB = h + (size_t)b * NN_ * DD;
    float vs[4] = {0.f, 0.f, 0.f, 0.f};
    float vm[4] = {-INFINITY, -INFINITY, -INFINITY, -INFINITY};

    #pragma unroll
    for (int pp = 0; pp < 2; ++pp) {             // j halves: 64 rows each
        f4 acc[4][4] = {};
        #pragma unroll
        for (int ks = 0; ks < 2; ++ks) {
            bs8 afr[4];
            #pragma unroll
            for (int m = 0; m < 4; ++m) {
                int j = pp * 64 + m * 16 + lcol;
                int k0 = ks * 32 + lrow * 8;
                afr[m] = *(const bs8*)(sHid + (j * 32 + ((k0 >> 1) ^ ((j & 7) << 2))));
            }
            #pragma unroll
            for (int m = 0; m < 4; ++m)
                #pragma unroll
                for (int nt = 0; nt < 4; ++nt)
                    acc[m][nt] = __builtin_amdgcn_mfma_f32_16x16x32_bf16(
                        afr[m], bfr[nt][ks], acc[m][nt], 0, 0, 0);
        }
        const unsigned long long mw = pp ? m1 : m0;
        #pragma unroll
        for (int m = 0; m < 4; ++m) {
            #pragma unroll
            for (int nt = 0; nt < 4; ++nt) {
                int dnt = w * 64 + nt * 16 + lcol;
                #pragma unroll
                for (int r = 0; r < 4; ++r) {
                    int bit = m * 16 + lrow * 4 + r;
                    float x = acc[m][nt][r] + bg[nt];
                    float g = 1.0f / (1.0f + __expf(-x));
                    float msg = g * hB[(pp * 64 + bit) * DD + dnt];
                    int on = (int)((mw >> bit) & 1ULL);
                    vs[nt] += on ? msg : 0.f;
                    vm[nt] = fmaxf(vm[nt], on ? msg : -INFINITY);
                }
            }
        }
    }

    // ---- cross-row-group reduce (lanes 16,32 apart) & write ----
    #pragma unroll
    for (int nt = 0; nt < 4; ++nt) {
        float s = vs[nt];
        s += __shfl_xor(s, 16); s += __shfl_xor(s, 32);
        vs[nt] = s;
        float m = vm[nt];
        m = fmaxf(m, __shfl_xor(m, 16)); m = fmaxf(m, __shfl_xor(m, 32));
        vm[nt] = m;
    }
    const int g = lrow;
    float ssel = (g == 0) ? vs[0] : (g == 1) ? vs[1] : (g == 2) ? vs[2] : vs[3];
    float msel = (g == 0) ? vm[0] : (g == 1) ? vm[1] : (g == 2) ? vm[2] : vm[3];
    const int d = w * 64 + lane;                 // = w*64 + g*16 + lcol
    agg_mean[(size_t)bi * DD + d] = ssel / fmaxf(cntf, 1.f);
    agg_max[(size_t)bi * DD + d] = (cntf > 0.f) ? msel : 0.f;
}

// ---------------- update MLP + residual + layernorm (in-place on h) ----------------
__global__ __launch_bounds__(256) void k_update(
    const float* __restrict__ agg_mean, const float* __restrict__ agg_max,
    const float* __restrict__ uw1, const float* __restrict__ ub1,
    const float* __restrict__ uw2, const float* __restrict__ ub2,
    const float* __restrict__ lng, const float* __restrict__ lnb,
    float* __restrict__ h, float* __restrict__ out2)
{
    const int tid = threadIdx.x;
    const int row0 = blockIdx.x * 4;
    __shared__ float sUi[4][3 * DD];
    __shared__ float sHid[4][DD];
    __shared__ float sRed[256];
    for (int idx = tid; idx < 4 * 3 * DD; idx += 256) {
        int r = idx / (3 * DD), k = idx % (3 * DD);
        int row = row0 + r;
        float v;
        if (k < DD)            v = h[(size_t)row * DD + k];
        else if (k < 2 * DD)   v = agg_mean[(size_t)row * DD + (k - DD)];
        else                   v = agg_max[(size_t)row * DD + (k - 2 * DD)];
        sUi[r][k] = v;
    }
    __syncthreads();
    float b1 = ub1[tid];
    float a0 = b1, a1 = b1, a2 = b1, a3 = b1;
    for (int k = 0; k < 3 * DD; ++k) {
        float wv = uw1[k * DD + tid];
        a0 += sUi[0][k] * wv; a1 += sUi[1][k] * wv;
        a2 += sUi[2][k] * wv; a3 += sUi[3][k] * wv;
    }
    sHid[0][tid] = fmaxf(a0, 0.f); sHid[1][tid] = fmaxf(a1, 0.f);
    sHid[2][tid] = fmaxf(a2, 0.f); sHid[3][tid] = fmaxf(a3, 0.f);
    __syncthreads();
    float b2 = ub2[tid];
    float x[4] = {b2, b2, b2, b2};
    for (int k = 0; k < DD; ++k) {
        float wv = uw2[k * DD + tid];
        x[0] += sHid[0][k] * wv; x[1] += sHid[1][k] * wv;
        x[2] += sHid[2][k] * wv; x[3] += sHid[3][k] * wv;
    }
    #pragma unroll
    for (int r = 0; r < 4; ++r) x[r] += h[(size_t)(row0 + r) * DD + tid];
    const float g = lng[tid], be = lnb[tid];
    for (int r = 0; r < 4; ++r) {
        float mu = blockReduceSum(x[r], sRed) * (1.f / DD);
        float dc = x[r] - mu;
        float var = blockReduceSum(dc * dc, sRed) * (1.f / DD);
        float res = dc * rsqrtf(var + 1e-5f) * g + be;
        h[(size_t)(row0 + r) * DD + tid] = res;
        if (out2) out2[(size_t)(row0 + r) * DD + tid] = res;
    }
}

// ---------------- graph embed ----------------
__global__ __launch_bounds__(256) void k_gembed(
    const float* __restrict__ nf, const float* __restrict__ h, float* __restrict__ ge)
{
    const int b = blockIdx.x, tid = threadIdx.x;
    __shared__ float sW[NN_];
    __shared__ float sRed[256];
    if (tid < NN_) {
        const float* p = nf + ((size_t)b * NN_ + tid) * 11;
        sW[tid] = p[0] * p[7];
    }
    __syncthreads();
    float part = (tid < NN_) ? sW[tid] : 0.f;
    float wsum = blockReduceSum(part, sRed);
    float acc = 0.f;
    for (int n = 0; n < NN_; ++n) acc += sW[n] * h[((size_t)b * NN_ + n) * DD + tid];
    ge[b * DD + tid] = acc / fmaxf(wsum, 1e-8f);
}

// ---------------- head stage 1: stacked GEMMs {query, stop-hidden, value-hidden} ----------------
__global__ __launch_bounds__(256) void k_head_mm(
    const float* __restrict__ ge, const float* __restrict__ le,
    const float* __restrict__ gd,
    const float* __restrict__ qw, const float* __restrict__ qb,
    const float* __restrict__ sw1, const float* __restrict__ sb1,
    const float* __restrict__ vw1, const float* __restrict__ vb1,
    float* __restrict__ query, float* __restrict__ sh, float* __restrict__ vh)
{
    const int blk = blockIdx.x;
    const int b = blk / 12, c = blk % 12;
    const int m = c >> 2, d0 = (c & 3) * 64;
    const int tid = threadIdx.x;
    const int d = tid & 63, ks = tid >> 6;
    __shared__ float sX[514];
    __shared__ float sP[4][64];
    if (m == 1) {
        sX[tid] = ge[b * DD + tid];
        if (tid < 2) sX[DD + tid] = gd[b * 2 + tid];
    } else {
        sX[tid] = ge[b * DD + tid];
        sX[DD + tid] = le[b * DD + tid];
        if (tid < 2) sX[2 * DD + tid] = gd[b * 2 + tid];
    }
    __syncthreads();
    const int K = (m == 1) ? 258 : 514;
    const float* W = (m == 0) ? qw : (m == 1) ? sw1 : vw1;
    float acc = 0.f;
    for (int k = ks; k < K; k += 4) acc += sX[k] * W[(size_t)k * DD + d0 + d];
    sP[ks][d] = acc;
    __syncthreads();
    if (ks == 0) {
        float a = sP[0][d] + sP[1][d] + sP[2][d] + sP[3][d];
        int od = d0 + d;
        if (m == 0)      query[b * DD + od] = a + qb[od];
        else if (m == 1) sh[b * DD + od] = fmaxf(a + sb1[od], 0.f);
        else             vh[b * DD + od] = fmaxf(a + vb1[od], 0.f);
    }
}

// ---------------- head stage 2: stop / value reductions ----------------
__global__ __launch_bounds__(256) void k_head_fin(
    const float* __restrict__ sh, const float* __restrict__ vh,
    const float* __restrict__ sw2, const float* __restrict__ sb2,
    const float* __restrict__ vw2, const float* __restrict__ vb2,
    float* __restrict__ out)
{
    const int b = blockIdx.x, tid = threadIdx.x;
    __shared__ float sRed[256];
    float stop = blockReduceSum(sh[b * DD + tid] * sw2[tid], sRed);
    float val  = blockReduceSum(vh[b * DD + tid] * vw2[tid], sRed);
    if (tid == 0) {
        out[b * 129 + 128] = stop + sb2[0];
        out[1032 + b] = val + vb2[0];
    }
}

// ---------------- device scores ----------------
__global__ __launch_bounds__(256) void k_scores(
    const float* __restrict__ h, const float* __restrict__ kw,
    const float* __restrict__ kb, const float* __restrict__ query,
    float* __restrict__ out)
{
    const int tid = threadIdx.x;
    const int row0 = blockIdx.x * 4;   // b*N + n
    __shared__ float sH[4][DD];
    __shared__ float sRed[256];
    for (int idx = tid; idx < 4 * DD; idx += 256)
        sH[idx >> 8][idx & 255] = h[(size_t)row0 * DD + idx];
    __syncthreads();
    float bb = kb[tid];
    float a0 = bb, a1 = bb, a2 = bb, a3 = bb;
    for (int k = 0; k < DD; ++k) {
        float wv = kw[k * DD + tid];
        a0 += sH[0][k] * wv; a1 += sH[1][k] * wv;
        a2 += sH[2][k] * wv; a3 += sH[3][k] * wv;
    }
    const int b = row0 >> 7;
    const float q = query[b * DD + tid];
    float s0 = blockReduceSum(a0 * q, sRed);
    float s1 = blockReduceSum(a1 * q, sRed);
    float s2 = blockReduceSum(a2 * q, sRed);
    float s3 = blockReduceSum(a3 * q, sRed);
    if (tid == 0) {
        int n0 = row0 & (NN_ - 1);
        out[b * 129 + n0 + 0] = s0 * 0.0625f;
        out[b * 129 + n0 + 1] = s1 * 0.0625f;
        out[b * 129 + n0 + 2] = s2 * 0.0625f;
        out[b * 129 + n0 + 3] = s3 * 0.0625f;
    }
}

extern "C" void kernel_launch(void* const* d_in, const int* in_sizes, int n_in,
                              void* d_out, int out_size, void* d_ws, size_t ws_size,
                              hipStream_t stream) {
    (void)in_sizes; (void)n_in; (void)out_size; (void)ws_size;
    const float* nf  = (const float*)d_in[0];
    const float* ef  = (const float*)d_in[1];
    const void*  adj = d_in[2];                 // dtype probed on device
    const float* lc  = (const float*)d_in[3];
    const float* gd  = (const float*)d_in[4];
    const float* pnw = (const float*)d_in[5];
    const float* pnb = (const float*)d_in[6];
    const float* gw1 = (const float*)d_in[7];
    const float* gb1 = (const float*)d_in[8];
    const float* gw2 = (const float*)d_in[9];
    const float* gb2 = (const float*)d_in[10];
    const float* uw1 = (const float*)d_in[11];
    const float* ub1 = (const float*)d_in[12];
    const float* uw2 = (const float*)d_in[13];
    const float* ub2 = (const float*)d_in[14];
    const float* lng = (const float*)d_in[15];
    const float* lnb = (const float*)d_in[16];
    const float* cw  = (const float*)d_in[17];
    const float* cb  = (const float*)d_in[18];
    const float* lpw = (const float*)d_in[19];
    const float* lpb = (const float*)d_in[20];
    const float* qw  = (const float*)d_in[21];
    const float* qb  = (const float*)d_in[22];
    const float* kw  = (const float*)d_in[23];
    const float* kb  = (const float*)d_in[24];
    const float* sw1 = (const float*)d_in[25];
    const float* sb1 = (const float*)d_in[26];
    const float* sw2 = (const float*)d_in[27];
    const float* sb2 = (const float*)d_in[28];
    const float* vw1 = (const float*)d_in[29];
    const float* vb1 = (const float*)d_in[30];
    const float* vw2 = (const float*)d_in[31];
    const float* vb2 = (const float*)d_in[32];

    float* ws = (float*)d_ws;
    float* h     = ws;                         // 262144
    float* preg  = ws + 262144;                // 65536
    float* amean = ws + 327680;                // 262144 (also k_lmm partials early)
    float* amax  = ws + 589824;                // 262144 (also conv buffer early)
    float* le    = ws + 851968;                // 2048
    float* ge    = ws + 854016;                // 2048
    float* query = ws + 856064;                // 2048
    float* sh    = ws + 858112;                // 2048
    float* vh    = ws + 860160;                // 2048
    int*   mode  = (int*)(ws + 862208);        // 1
    float* conv  = amax;                       // 7936 floats, pre-layer only
    float* lpart = amean;                      // 16384 floats, pre-layer only
    float* out   = (float*)d_out;

    k_detect<<<1, 256, 0, stream>>>((const unsigned char*)adj, mode);
    k_nodeproj<<<BB * NN_, 256, 0, stream>>>(nf, pnw, pnb, h);
    k_conv<<<BB, 256, 0, stream>>>(lc, cw, cb, conv);
    k_lmm<<<256, 256, 0, stream>>>(conv, lpw, lpart);
    k_lred<<<BB, 256, 0, stream>>>(lpart, lpb, le);
    for (int i = 0; i < NG; ++i) {
        const float* gw1i = gw1 + (size_t)i * 259 * EH;
        k_pregate<<<BB * NN_ / 4, 256, 0, stream>>>(h, gw1i, gb1 + i * EH, preg);
        k_edge<<<BB * NN_, 256, 0, stream>>>(h, preg, ef, adj, mode, gw1i,
                                             gw2 + (size_t)i * EH * DD, gb2 + i * DD,
                                             amean, amax);
        k_update<<<BB * NN_ / 4, 256, 0, stream>>>(amean, amax,
                                                   uw1 + (size_t)i * 3 * DD * DD, ub1 + i * DD,
                                                   uw2 + (size_t)i * DD * DD, ub2 + i * DD,
                                                   lng + i * DD, lnb + i * DD, h,
                                                   (i == NG - 1) ? (out + 1040) : (float*)nullptr);
    }
    k_gembed<<<BB, 256, 0, stream>>>(nf, h, ge);
    k_head_mm<<<BB * 12, 256, 0, stream>>>(ge, le, gd, qw, qb, sw1, sb1, vw1, vb1,
                                           query, sh, vh);
    k_head_fin<<<BB, 256, 0, stream>>>(sh, vh, sw2, sb2, vw2, vb2, out);
    k_scores<<<BB * NN_ / 4, 256, 0, stream>>>(h, kw, kb, query, out);
}

// Round 5
// 269.375 us; speedup vs baseline: 2.1501x; 1.2922x over previous
//
#include <hip/hip_runtime.h>
#include <hip/hip_bf16.h>
#include <math.h>

// Problem constants
#define BB 8
#define NN_ 128
#define DD 256
#define LL 64
#define EH 64
#define NG 3

typedef __attribute__((ext_vector_type(8))) short bs8;   // 8 bf16 (4 VGPR)
typedef __attribute__((ext_vector_type(4))) float f4;    // 4 f32

__device__ __forceinline__ short f2bf(float f) {
    __hip_bfloat16 h = __float2bfloat16(f);
    return *reinterpret_cast<short*>(&h);
}

// ---------------- helpers ----------------
__device__ __forceinline__ float blockReduceSum(float v, float* sRed) {
    int tid = threadIdx.x;
    __syncthreads();
    sRed[tid] = v;
    __syncthreads();
    for (int s = 128; s > 0; s >>= 1) {
        if (tid < s) sRed[tid] += sRed[tid + s];
        __syncthreads();
    }
    return sRed[0];
}

// ---------------- adj dtype probe: 0 = bool8, 1 = int32, 2 = float32 ----------------
__global__ __launch_bounds__(256) void k_detect(const unsigned char* __restrict__ adj,
                                                int* __restrict__ mode) {
    __shared__ int sOff, sBig;
    const int tid = threadIdx.x;
    if (tid == 0) { sOff = 0; sBig = 0; }
    __syncthreads();
    int off = 0, big = 0;
    #pragma unroll
    for (int k = 0; k < 4; ++k) {
        unsigned char v = adj[tid * 4 + k];
        if (v > 1) big = 1;
        if (k != 0 && v != 0) off = 1;
    }
    if (off) atomicOr(&sOff, 1);
    if (big) atomicOr(&sBig, 1);
    __syncthreads();
    if (tid == 0) mode[0] = sBig ? 2 : (sOff ? 0 : 1);
}

// ---------------- weight prep: transpose + f32->bf16 for update MLP ----------------
// uw1 [3][768][256] -> w1t [3][256][768] bf16 ; uw2 [3][256][256] -> w2t [3][256][256] bf16
__global__ __launch_bounds__(256) void k_prep(
    const float* __restrict__ uw1, const float* __restrict__ uw2,
    unsigned short* __restrict__ w1t, unsigned short* __restrict__ w2t)
{
    const int blk = blockIdx.x, tid = threadIdx.x;
    const float* src; unsigned short* dst; int K, kt, dt;
    if (blk < 144) {
        int l = blk / 48, t = blk % 48; kt = t >> 2; dt = t & 3;
        src = uw1 + (size_t)l * 768 * 256; dst = w1t + (size_t)l * 256 * 768; K = 768;
    } else {
        int x = blk - 144; int l = x / 16, t = x % 16; kt = t >> 2; dt = t & 3;
        src = uw2 + (size_t)l * 65536; dst = w2t + (size_t)l * 65536; K = 256;
    }
    __shared__ float sT[64][65];
    #pragma unroll
    for (int q = 0; q < 16; ++q) {
        int idx = q * 256 + tid;
        int kk = idx >> 6, dd = idx & 63;
        sT[kk][dd] = src[(size_t)(kt * 64 + kk) * 256 + dt * 64 + dd];
    }
    __syncthreads();
    const int d = tid >> 2, kc = (tid & 3) * 16;
    unsigned short* drow = dst + (size_t)(dt * 64 + d) * K + kt * 64 + kc;
    #pragma unroll
    for (int i = 0; i < 16; ++i) drow[i] = (unsigned short)f2bf(sT[kc + i][d]);
}

// ---------------- node projection: h = nf @ p_node_w + b ----------------
__global__ __launch_bounds__(256) void k_nodeproj(
    const float* __restrict__ nf, const float* __restrict__ w,
    const float* __restrict__ bias, float* __restrict__ h)
{
    const int row = blockIdx.x, tid = threadIdx.x;
    __shared__ float sF[11];
    if (tid < 11) sF[tid] = nf[(size_t)row * 11 + tid];
    __syncthreads();
    float a = bias[tid];
    #pragma unroll
    for (int f = 0; f < 11; ++f) a += sF[f] * w[f * DD + tid];
    h[(size_t)row * DD + tid] = a;
}

// ---------------- layer-cost encoder stage A: conv1d + relu ----------------
__global__ __launch_bounds__(256) void k_conv(
    const float* __restrict__ lc, const float* __restrict__ cw,
    const float* __restrict__ cb, float* __restrict__ conv)
{
    const int b = blockIdx.x, tid = threadIdx.x;
    __shared__ float sC[LL];
    if (tid < LL) sC[tid] = lc[b * LL + tid];
    __syncthreads();
    for (int idx = tid; idx < 992; idx += 256) {
        int c = idx / 31, t = idx % 31;
        float a = cb[c];
        #pragma unroll
        for (int k = 0; k < 4; ++k) a += sC[2 * t + k] * cw[c * 4 + k];
        conv[b * 992 + idx] = fmaxf(a, 0.f);
    }
}

// ---------------- stage B: split-k GEMM [8x992]@[992x256] -> partials ----------------
__global__ __launch_bounds__(256) void k_lmm(
    const float* __restrict__ conv, const float* __restrict__ lpw,
    float* __restrict__ part)
{
    const int blk = blockIdx.x;
    const int b = blk >> 5, kseg = (blk >> 2) & 7, c4 = blk & 3;
    const int tid = threadIdx.x;
    const int d = tid & 63, ss = tid >> 6;
    __shared__ float sV[124];
    __shared__ float sP[4][64];
    if (tid < 124) sV[tid] = conv[b * 992 + kseg * 124 + tid];
    __syncthreads();
    float acc = 0.f;
    for (int k = ss; k < 124; k += 4)
        acc += sV[k] * lpw[(size_t)(kseg * 124 + k) * DD + c4 * 64 + d];
    sP[ss][d] = acc;
    __syncthreads();
    if (ss == 0)
        part[(b * 32 + kseg * 4 + c4) * 64 + d] = sP[0][d] + sP[1][d] + sP[2][d] + sP[3][d];
}

// ---------------- stage C: reduce partials + bias ----------------
__global__ __launch_bounds__(256) void k_lred(
    const float* __restrict__ part, const float* __restrict__ lpb,
    float* __restrict__ le)
{
    const int b = blockIdx.x, tid = threadIdx.x;
    const int c4 = tid >> 6, d = tid & 63;
    float a = lpb[tid];
    #pragma unroll
    for (int kseg = 0; kseg < 8; ++kseg)
        a += part[(b * 32 + kseg * 4 + c4) * 64 + d];
    le[b * DD + tid] = a;
}

// ---------------- per-layer: preg = h @ gw1[:256] + gb1 (no relu yet) ----------------
__global__ __launch_bounds__(256) void k_pregate(
    const float* __restrict__ h, const float* __restrict__ gw1,
    const float* __restrict__ gb1, float* __restrict__ preg)
{
    const int tid = threadIdx.x;
    const int row0 = blockIdx.x * 4;
    const int r = tid >> 6, t = tid & 63;
    __shared__ float sH[4][DD];
    for (int idx = tid; idx < 4 * DD; idx += 256)
        sH[idx >> 8][idx & 255] = h[(size_t)row0 * DD + idx];
    __syncthreads();
    float a = gb1[t];
    for (int k = 0; k < DD; ++k) a += sH[r][k] * gw1[k * EH + t];
    preg[(size_t)(row0 + r) * EH + t] = a;
}

// ---------------- fused edge-gate (MFMA) + masked aggregation ----------------
__global__ __launch_bounds__(256) void k_edge(
    const float* __restrict__ h, const float* __restrict__ preg,
    const float* __restrict__ edge, const void* __restrict__ adj,
    const int* __restrict__ mode,
    const float* __restrict__ gw1,
    const float* __restrict__ gw2,
    const float* __restrict__ gb2,
    float* __restrict__ agg_mean, float* __restrict__ agg_max)
{
    const int tid = threadIdx.x;
    const int bi = blockIdx.x;
    const int b = bi >> 7;
    const int lane = tid & 63, w = tid >> 6;
    const int lrow = lane >> 4, lcol = lane & 15;
    const int md = mode[0];

    __shared__ __align__(16) unsigned int sHid[4096];
    __shared__ __align__(16) unsigned short sB[16384];
    __shared__ float sWe[192];
    __shared__ float sE[384];
    __shared__ unsigned long long sMask[2];

    if (tid < 192) sWe[tid] = gw1[16384 + tid];
    const float* eB = edge + (size_t)bi * 384;
    for (int idx = tid; idx < 384; idx += 256) sE[idx] = eB[idx];
    if (tid < 128) {
        int mv;
        if (md == 1)      mv = ((const int*)adj)[(size_t)bi * NN_ + tid] != 0;
        else if (md == 2) mv = ((const float*)adj)[(size_t)bi * NN_ + tid] != 0.f;
        else              mv = ((const unsigned char*)adj)[(size_t)bi * NN_ + tid] != 0;
        unsigned long long bal = __ballot(mv);
        if ((tid & 63) == 0) sMask[tid >> 6] = bal;
    }
    __syncthreads();

    const float* pB = preg + (size_t)b * NN_ * EH;
    #pragma unroll
    for (int q = 0; q < 16; ++q) {
        int idx = q * 256 + tid;
        int j = idx >> 5, p = idx & 31;
        float2 pv = *(const float2*)(pB + j * EH + 2 * p);
        float e0 = sE[j * 3], e1 = sE[j * 3 + 1], e2 = sE[j * 3 + 2];
        int t0 = 2 * p, t1 = t0 + 1;
        float v0 = fmaxf(pv.x + e0 * sWe[t0] + e1 * sWe[64 + t0] + e2 * sWe[128 + t0], 0.f);
        float v1 = fmaxf(pv.y + e0 * sWe[t1] + e1 * sWe[64 + t1] + e2 * sWe[128 + t1], 0.f);
        unsigned int pk = (unsigned int)(unsigned short)f2bf(v0) |
                          ((unsigned int)(unsigned short)f2bf(v1) << 16);
        sHid[j * 32 + (p ^ ((j & 7) << 2))] = pk;
    }
    #pragma unroll
    for (int q = 0; q < 64; ++q) {
        int idx = q * 256 + tid;
        int k = idx >> 8, d = idx & 255;
        sB[(d * 64 + k) ^ ((d & 7) << 3)] = (unsigned short)f2bf(gw2[idx]);
    }
    __syncthreads();

    const unsigned long long m0 = sMask[0], m1 = sMask[1];
    const float cntf = (float)(__popcll(m0) + __popcll(m1));

    bs8 bfr[4][2];
    float bg[4];
    #pragma unroll
    for (int nt = 0; nt < 4; ++nt) {
        int d = w * 64 + nt * 16 + lcol;
        bg[nt] = gb2[d];
        #pragma unroll
        for (int ks = 0; ks < 2; ++ks) {
            int k0 = ks * 32 + lrow * 8;
            bfr[nt][ks] = *(const bs8*)(sB + ((d * 64 + k0) ^ ((d & 7) << 3)));
        }
    }

    const float* hB = h + (size_t)b * NN_ * DD;
    float vs[4] = {0.f, 0.f, 0.f, 0.f};
    float vm[4] = {-INFINITY, -INFINITY, -INFINITY, -INFINITY};

    #pragma unroll
    for (int pp = 0; pp < 2; ++pp) {
        f4 acc[4][4] = {};
        #pragma unroll
        for (int ks = 0; ks < 2; ++ks) {
            bs8 afr[4];
            #pragma unroll
            for (int m = 0; m < 4; ++m) {
                int j = pp * 64 + m * 16 + lcol;
                int k0 = ks * 32 + lrow * 8;
                afr[m] = *(const bs8*)(sHid + (j * 32 + ((k0 >> 1) ^ ((j & 7) << 2))));
            }
            #pragma unroll
            for (int m = 0; m < 4; ++m)
                #pragma unroll
                for (int nt = 0; nt < 4; ++nt)
                    acc[m][nt] = __builtin_amdgcn_mfma_f32_16x16x32_bf16(
                        afr[m], bfr[nt][ks], acc[m][nt], 0, 0, 0);
        }
        const unsigned long long mw = pp ? m1 : m0;
        #pragma unroll
        for (int m = 0; m < 4; ++m) {
            #pragma unroll
            for (int nt = 0; nt < 4; ++nt) {
                int dnt = w * 64 + nt * 16 + lcol;
                #pragma unroll
                for (int r = 0; r < 4; ++r) {
                    int bit = m * 16 + lrow * 4 + r;
                    float x = acc[m][nt][r] + bg[nt];
                    float g = 1.0f / (1.0f + __expf(-x));
                    float msg = g * hB[(pp * 64 + bit) * DD + dnt];
                    int on = (int)((mw >> bit) & 1ULL);
                    vs[nt] += on ? msg : 0.f;
                    vm[nt] = fmaxf(vm[nt], on ? msg : -INFINITY);
                }
            }
        }
    }

    #pragma unroll
    for (int nt = 0; nt < 4; ++nt) {
        float s = vs[nt];
        s += __shfl_xor(s, 16); s += __shfl_xor(s, 32);
        vs[nt] = s;
        float m = vm[nt];
        m = fmaxf(m, __shfl_xor(m, 16)); m = fmaxf(m, __shfl_xor(m, 32));
        vm[nt] = m;
    }
    const int g = lrow;
    float ssel = (g == 0) ? vs[0] : (g == 1) ? vs[1] : (g == 2) ? vs[2] : vs[3];
    float msel = (g == 0) ? vm[0] : (g == 1) ? vm[1] : (g == 2) ? vm[2] : vm[3];
    const int d = w * 64 + lane;
    agg_mean[(size_t)bi * DD + d] = ssel / fmaxf(cntf, 1.f);
    agg_max[(size_t)bi * DD + d] = (cntf > 0.f) ? msel : 0.f;
}

// ---------------- MFMA update MLP + residual + LN ----------------
// block = 4 rows, 4 waves; wave w = cols [w*64, w*64+64). Weights pre-transposed bf16.
__global__ __launch_bounds__(256) void k_upd(
    const float* __restrict__ h, const float* __restrict__ amean,
    const float* __restrict__ amax,
    const unsigned short* __restrict__ w1t,   // [256d][768k] bf16
    const float* __restrict__ ub1,
    const unsigned short* __restrict__ w2t,   // [256d][256k] bf16
    const float* __restrict__ ub2,
    const float* __restrict__ lng, const float* __restrict__ lnb,
    float* __restrict__ hout, float* __restrict__ out2)
{
    const int tid = threadIdx.x;
    const int row0 = blockIdx.x * 4;
    const int lane = tid & 63, w = tid >> 6;
    const int lcol = lane & 15, lrow = lane >> 4;

    __shared__ __align__(16) unsigned int sX32[16 * 384];     // bf16[16][768] swz (rows 4-15 unused)
    __shared__ __align__(16) unsigned short sH16[16 * 256];   // bf16[16][256] swz
    __shared__ float sRes[4][256];
    __shared__ float sOut[4][256];

    // ---- stage X rows: wave w stages row w: [h | amean | amax] -> bf16 swz ----
    {
        const int j = w;
        const float* hR = h + (size_t)(row0 + j) * DD;
        const float* mR = amean + (size_t)(row0 + j) * DD;
        const float* xR = amax + (size_t)(row0 + j) * DD;
        #pragma unroll
        for (int q = 0; q < 6; ++q) {
            int p = lane + q * 64;           // pair index 0..383
            int k = 2 * p;
            float2 v;
            if (k < 256)      { v = *(const float2*)(hR + k); sRes[j][k] = v.x; sRes[j][k + 1] = v.y; }
            else if (k < 512)   v = *(const float2*)(mR + (k - 256));
            else                v = *(const float2*)(xR + (k - 512));
            unsigned int pk = (unsigned int)(unsigned short)f2bf(v.x) |
                              ((unsigned int)(unsigned short)f2bf(v.y) << 16);
            sX32[j * 384 + (p ^ (j << 2))] = pk;
        }
    }
    __syncthreads();

    // ---- GEMM1: X[16x768] @ W1T -> hidden cols w*64.. (acc per nt) ----
    const char* sXb = (const char*)sX32;
    const unsigned short* w1r = w1t + (size_t)(w * 64 + lcol) * 768;
    f4 a0 = {0.f, 0.f, 0.f, 0.f}, a1 = a0, a2 = a0, a3 = a0;
    #pragma unroll 4
    for (int ks = 0; ks < 24; ++ks) {
        int k0 = ks * 32 + lrow * 8;
        bs8 av = *(const bs8*)(sXb + lcol * 1536 + ((((k0 >> 3) ^ (lcol & 7))) << 4));
        bs8 b0 = *(const bs8*)(w1r + k0);
        bs8 b1 = *(const bs8*)(w1r + 16 * 768 + k0);
        bs8 b2 = *(const bs8*)(w1r + 32 * 768 + k0);
        bs8 b3 = *(const bs8*)(w1r + 48 * 768 + k0);
        a0 = __builtin_amdgcn_mfma_f32_16x16x32_bf16(av, b0, a0, 0, 0, 0);
        a1 = __builtin_amdgcn_mfma_f32_16x16x32_bf16(av, b1, a1, 0, 0, 0);
        a2 = __builtin_amdgcn_mfma_f32_16x16x32_bf16(av, b2, a2, 0, 0, 0);
        a3 = __builtin_amdgcn_mfma_f32_16x16x32_bf16(av, b3, a3, 0, 0, 0);
    }
    // epilogue: lanes 0-15 hold rows 0-3; relu+bias -> sH bf16 swz
    if (lrow == 0) {
        #pragma unroll
        for (int nt = 0; nt < 4; ++nt) {
            int d = w * 64 + nt * 16 + lcol;
            float bb = ub1[d];
            f4 A = (nt == 0) ? a0 : (nt == 1) ? a1 : (nt == 2) ? a2 : a3;
            #pragma unroll
            for (int r = 0; r < 4; ++r) {
                float hv = fmaxf(A[r] + bb, 0.f);
                sH16[r * 256 + (d ^ (r << 3))] = (unsigned short)f2bf(hv);
            }
        }
    }
    __syncthreads();

    // ---- GEMM2: hidden[16x256] @ W2T ----
    const unsigned short* w2r = w2t + (size_t)(w * 64 + lcol) * 256;
    f4 c0 = {0.f, 0.f, 0.f, 0.f}, c1 = c0, c2 = c0, c3 = c0;
    #pragma unroll
    for (int ks = 0; ks < 8; ++ks) {
        int k0 = ks * 32 + lrow * 8;
        bs8 av = *(const bs8*)((const char*)sH16 + lcol * 512 + ((((k0 >> 3) ^ (lcol & 7))) << 4));
        bs8 b0 = *(const bs8*)(w2r + k0);
        bs8 b1 = *(const bs8*)(w2r + 16 * 256 + k0);
        bs8 b2 = *(const bs8*)(w2r + 32 * 256 + k0);
        bs8 b3 = *(const bs8*)(w2r + 48 * 256 + k0);
        c0 = __builtin_amdgcn_mfma_f32_16x16x32_bf16(av, b0, c0, 0, 0, 0);
        c1 = __builtin_amdgcn_mfma_f32_16x16x32_bf16(av, b1, c1, 0, 0, 0);
        c2 = __builtin_amdgcn_mfma_f32_16x16x32_bf16(av, b2, c2, 0, 0, 0);
        c3 = __builtin_amdgcn_mfma_f32_16x16x32_bf16(av, b3, c3, 0, 0, 0);
    }
    if (lrow == 0) {
        #pragma unroll
        for (int nt = 0; nt < 4; ++nt) {
            int d = w * 64 + nt * 16 + lcol;
            float bb = ub2[d];
            f4 C = (nt == 0) ? c0 : (nt == 1) ? c1 : (nt == 2) ? c2 : c3;
            #pragma unroll
            for (int r = 0; r < 4; ++r)
                sOut[r][d] = C[r] + bb + sRes[r][d];
        }
    }
    __syncthreads();

    // ---- LN: wave w handles row w (two-pass, shfl-only) ----
    float xv[4], s = 0.f;
    #pragma unroll
    for (int q = 0; q < 4; ++q) { xv[q] = sOut[w][lane + 64 * q]; s += xv[q]; }
    #pragma unroll
    for (int off = 1; off < 64; off <<= 1) s += __shfl_xor(s, off);
    const float mu = s * (1.f / DD);
    float s2 = 0.f;
    #pragma unroll
    for (int q = 0; q < 4; ++q) { float d = xv[q] - mu; s2 += d * d; }
    #pragma unroll
    for (int off = 1; off < 64; off <<= 1) s2 += __shfl_xor(s2, off);
    const float inv = rsqrtf(s2 * (1.f / DD) + 1e-5f);
    #pragma unroll
    for (int q = 0; q < 4; ++q) {
        int c = lane + 64 * q;
        float res = (xv[q] - mu) * inv * lng[c] + lnb[c];
        hout[(size_t)(row0 + w) * DD + c] = res;
        if (out2) out2[(size_t)(row0 + w) * DD + c] = res;
    }
}

// ---------------- fallback f32 update (ws too small) ----------------
__global__ __launch_bounds__(256) void k_update(
    const float* __restrict__ agg_mean, const float* __restrict__ agg_max,
    const float* __restrict__ uw1, const float* __restrict__ ub1,
    const float* __restrict__ uw2, const float* __restrict__ ub2,
    const float* __restrict__ lng, const float* __restrict__ lnb,
    float* __restrict__ h, float* __restrict__ out2)
{
    const int tid = threadIdx.x;
    const int row0 = blockIdx.x * 4;
    __shared__ float sUi[4][3 * DD];
    __shared__ float sHid[4][DD];
    __shared__ float sRed[256];
    for (int idx = tid; idx < 4 * 3 * DD; idx += 256) {
        int r = idx / (3 * DD), k = idx % (3 * DD);
        int row = row0 + r;
        float v;
        if (k < DD)            v = h[(size_t)row * DD + k];
        else if (k < 2 * DD)   v = agg_mean[(size_t)row * DD + (k - DD)];
        else                   v = agg_max[(size_t)row * DD + (k - 2 * DD)];
        sUi[r][k] = v;
    }
    __syncthreads();
    float b1 = ub1[tid];
    float a0 = b1, a1 = b1, a2 = b1, a3 = b1;
    for (int k = 0; k < 3 * DD; ++k) {
        float wv = uw1[k * DD + tid];
        a0 += sUi[0][k] * wv; a1 += sUi[1][k] * wv;
        a2 += sUi[2][k] * wv; a3 += sUi[3][k] * wv;
    }
    sHid[0][tid] = fmaxf(a0, 0.f); sHid[1][tid] = fmaxf(a1, 0.f);
    sHid[2][tid] = fmaxf(a2, 0.f); sHid[3][tid] = fmaxf(a3, 0.f);
    __syncthreads();
    float b2 = ub2[tid];
    float x[4] = {b2, b2, b2, b2};
    for (int k = 0; k < DD; ++k) {
        float wv = uw2[k * DD + tid];
        x[0] += sHid[0][k] * wv; x[1] += sHid[1][k] * wv;
        x[2] += sHid[2][k] * wv; x[3] += sHid[3][k] * wv;
    }
    #pragma unroll
    for (int r = 0; r < 4; ++r) x[r] += h[(size_t)(row0 + r) * DD + tid];
    const float g = lng[tid], be = lnb[tid];
    for (int r = 0; r < 4; ++r) {
        float mu = blockReduceSum(x[r], sRed) * (1.f / DD);
        float dc = x[r] - mu;
        float var = blockReduceSum(dc * dc, sRed) * (1.f / DD);
        float res = dc * rsqrtf(var + 1e-5f) * g + be;
        h[(size_t)(row0 + r) * DD + tid] = res;
        if (out2) out2[(size_t)(row0 + r) * DD + tid] = res;
    }
}

// ---------------- graph embed ----------------
__global__ __launch_bounds__(256) void k_gembed(
    const float* __restrict__ nf, const float* __restrict__ h, float* __restrict__ ge)
{
    const int b = blockIdx.x, tid = threadIdx.x;
    __shared__ float sW[NN_];
    __shared__ float sRed[256];
    if (tid < NN_) {
        const float* p = nf + ((size_t)b * NN_ + tid) * 11;
        sW[tid] = p[0] * p[7];
    }
    __syncthreads();
    float part = (tid < NN_) ? sW[tid] : 0.f;
    float wsum = blockReduceSum(part, sRed);
    float acc = 0.f;
    for (int n = 0; n < NN_; ++n) acc += sW[n] * h[((size_t)b * NN_ + n) * DD + tid];
    ge[b * DD + tid] = acc / fmaxf(wsum, 1e-8f);
}

// ---------------- head stage 1: stacked GEMMs {query, stop-hidden, value-hidden} ----------------
__global__ __launch_bounds__(256) void k_head_mm(
    const float* __restrict__ ge, const float* __restrict__ le,
    const float* __restrict__ gd,
    const float* __restrict__ qw, const float* __restrict__ qb,
    const float* __restrict__ sw1, const float* __restrict__ sb1,
    const float* __restrict__ vw1, const float* __restrict__ vb1,
    float* __restrict__ query, float* __restrict__ sh, float* __restrict__ vh)
{
    const int blk = blockIdx.x;
    const int b = blk / 12, c = blk % 12;
    const int m = c >> 2, d0 = (c & 3) * 64;
    const int tid = threadIdx.x;
    const int d = tid & 63, ks = tid >> 6;
    __shared__ float sX[514];
    __shared__ float sP[4][64];
    if (m == 1) {
        sX[tid] = ge[b * DD + tid];
        if (tid < 2) sX[DD + tid] = gd[b * 2 + tid];
    } else {
        sX[tid] = ge[b * DD + tid];
        sX[DD + tid] = le[b * DD + tid];
        if (tid < 2) sX[2 * DD + tid] = gd[b * 2 + tid];
    }
    __syncthreads();
    const int K = (m == 1) ? 258 : 514;
    const float* W = (m == 0) ? qw : (m == 1) ? sw1 : vw1;
    float acc = 0.f;
    for (int k = ks; k < K; k += 4) acc += sX[k] * W[(size_t)k * DD + d0 + d];
    sP[ks][d] = acc;
    __syncthreads();
    if (ks == 0) {
        float a = sP[0][d] + sP[1][d] + sP[2][d] + sP[3][d];
        int od = d0 + d;
        if (m == 0)      query[b * DD + od] = a + qb[od];
        else if (m == 1) sh[b * DD + od] = fmaxf(a + sb1[od], 0.f);
        else             vh[b * DD + od] = fmaxf(a + vb1[od], 0.f);
    }
}

// ---------------- head stage 2: stop / value reductions ----------------
__global__ __launch_bounds__(256) void k_head_fin(
    const float* __restrict__ sh, const float* __restrict__ vh,
    const float* __restrict__ sw2, const float* __restrict__ sb2,
    const float* __restrict__ vw2, const float* __restrict__ vb2,
    float* __restrict__ out)
{
    const int b = blockIdx.x, tid = threadIdx.x;
    __shared__ float sRed[256];
    float stop = blockReduceSum(sh[b * DD + tid] * sw2[tid], sRed);
    float val  = blockReduceSum(vh[b * DD + tid] * vw2[tid], sRed);
    if (tid == 0) {
        out[b * 129 + 128] = stop + sb2[0];
        out[1032 + b] = val + vb2[0];
    }
}

// ---------------- device scores ----------------
__global__ __launch_bounds__(256) void k_scores(
    const float* __restrict__ h, const float* __restrict__ kw,
    const float* __restrict__ kb, const float* __restrict__ query,
    float* __restrict__ out)
{
    const int tid = threadIdx.x;
    const int row0 = blockIdx.x * 4;
    __shared__ float sH[4][DD];
    __shared__ float sRed[256];
    for (int idx = tid; idx < 4 * DD; idx += 256)
        sH[idx >> 8][idx & 255] = h[(size_t)row0 * DD + idx];
    __syncthreads();
    float bb = kb[tid];
    float a0 = bb, a1 = bb, a2 = bb, a3 = bb;
    for (int k = 0; k < DD; ++k) {
        float wv = kw[k * DD + tid];
        a0 += sH[0][k] * wv; a1 += sH[1][k] * wv;
        a2 += sH[2][k] * wv; a3 += sH[3][k] * wv;
    }
    const int b = row0 >> 7;
    const float q = query[b * DD + tid];
    float s0 = blockReduceSum(a0 * q, sRed);
    float s1 = blockReduceSum(a1 * q, sRed);
    float s2 = blockReduceSum(a2 * q, sRed);
    float s3 = blockReduceSum(a3 * q, sRed);
    if (tid == 0) {
        int n0 = row0 & (NN_ - 1);
        out[b * 129 + n0 + 0] = s0 * 0.0625f;
        out[b * 129 + n0 + 1] = s1 * 0.0625f;
        out[b * 129 + n0 + 2] = s2 * 0.0625f;
        out[b * 129 + n0 + 3] = s3 * 0.0625f;
    }
}

extern "C" void kernel_launch(void* const* d_in, const int* in_sizes, int n_in,
                              void* d_out, int out_size, void* d_ws, size_t ws_size,
                              hipStream_t stream) {
    (void)in_sizes; (void)n_in; (void)out_size;
    const float* nf  = (const float*)d_in[0];
    const float* ef  = (const float*)d_in[1];
    const void*  adj = d_in[2];
    const float* lc  = (const float*)d_in[3];
    const float* gd  = (const float*)d_in[4];
    const float* pnw = (const float*)d_in[5];
    const float* pnb = (const float*)d_in[6];
    const float* gw1 = (const float*)d_in[7];
    const float* gb1 = (const float*)d_in[8];
    const float* gw2 = (const float*)d_in[9];
    const float* gb2 = (const float*)d_in[10];
    const float* uw1 = (const float*)d_in[11];
    const float* ub1 = (const float*)d_in[12];
    const float* uw2 = (const float*)d_in[13];
    const float* ub2 = (const float*)d_in[14];
    const float* lng = (const float*)d_in[15];
    const float* lnb = (const float*)d_in[16];
    const float* cw  = (const float*)d_in[17];
    const float* cb  = (const float*)d_in[18];
    const float* lpw = (const float*)d_in[19];
    const float* lpb = (const float*)d_in[20];
    const float* qw  = (const float*)d_in[21];
    const float* qb  = (const float*)d_in[22];
    const float* kw  = (const float*)d_in[23];
    const float* kb  = (const float*)d_in[24];
    const float* sw1 = (const float*)d_in[25];
    const float* sb1 = (const float*)d_in[26];
    const float* sw2 = (const float*)d_in[27];
    const float* sb2 = (const float*)d_in[28];
    const float* vw1 = (const float*)d_in[29];
    const float* vb1 = (const float*)d_in[30];
    const float* vw2 = (const float*)d_in[31];
    const float* vb2 = (const float*)d_in[32];

    float* ws = (float*)d_ws;
    float* h     = ws;                         // 262144
    float* preg  = ws + 262144;                // 65536
    float* amean = ws + 327680;                // 262144 (k_lmm partials early)
    float* amax  = ws + 589824;                // 262144 (conv buffer early)
    float* le    = ws + 851968;                // 2048
    float* ge    = ws + 854016;                // 2048
    float* query = ws + 856064;                // 2048
    float* sh    = ws + 858112;                // 2048
    float* vh    = ws + 860160;                // 2048
    int*   mode  = (int*)(ws + 862208);        // 1 (pad to 862212)
    unsigned short* uw1t = (unsigned short*)(ws + 862212);   // 589824 bf16
    unsigned short* uw2t = (unsigned short*)(ws + 1157124);  // 196608 bf16
    const size_t NEED = (size_t)1255428 * 4;
    const bool mfma_upd = ws_size >= NEED;
    float* conv  = amax;
    float* lpart = amean;
    float* out   = (float*)d_out;

    k_detect<<<1, 256, 0, stream>>>((const unsigned char*)adj, mode);
    if (mfma_upd) k_prep<<<192, 256, 0, stream>>>(uw1, uw2, uw1t, uw2t);
    k_nodeproj<<<BB * NN_, 256, 0, stream>>>(nf, pnw, pnb, h);
    k_conv<<<BB, 256, 0, stream>>>(lc, cw, cb, conv);
    k_lmm<<<256, 256, 0, stream>>>(conv, lpw, lpart);
    k_lred<<<BB, 256, 0, stream>>>(lpart, lpb, le);
    for (int i = 0; i < NG; ++i) {
        const float* gw1i = gw1 + (size_t)i * 259 * EH;
        float* out2sel = (i == NG - 1) ? (out + 1040) : (float*)nullptr;
        k_pregate<<<BB * NN_ / 4, 256, 0, stream>>>(h, gw1i, gb1 + i * EH, preg);
        k_edge<<<BB * NN_, 256, 0, stream>>>(h, preg, ef, adj, mode, gw1i,
                                             gw2 + (size_t)i * EH * DD, gb2 + i * DD,
                                             amean, amax);
        if (mfma_upd)
            k_upd<<<BB * NN_ / 4, 256, 0, stream>>>(h, amean, amax,
                                                    uw1t + (size_t)i * 196608, ub1 + i * DD,
                                                    uw2t + (size_t)i * 65536, ub2 + i * DD,
                                                    lng + i * DD, lnb + i * DD, h, out2sel);
        else
            k_update<<<BB * NN_ / 4, 256, 0, stream>>>(amean, amax,
                                                       uw1 + (size_t)i * 3 * DD * DD, ub1 + i * DD,
                                                       uw2 + (size_t)i * DD * DD, ub2 + i * DD,
                                                       lng + i * DD, lnb + i * DD, h, out2sel);
    }
    k_gembed<<<BB, 256, 0, stream>>>(nf, h, ge);
    k_head_mm<<<BB * 12, 256, 0, stream>>>(ge, le, gd, qw, qb, sw1, sb1, vw1, vb1,
                                           query, sh, vh);
    k_head_fin<<<BB, 256, 0, stream>>>(sh, vh, sw2, sb2, vw2, vb2, out);
    k_scores<<<BB * NN_ / 4, 256, 0, stream>>>(h, kw, kb, query, out);
}

// Round 6
// 216.432 us; speedup vs baseline: 2.6761x; 1.2446x over previous
//
#include <hip/hip_runtime.h>
#include <hip/hip_bf16.h>
#include <math.h>

// Problem constants
#define BB 8
#define NN_ 128
#define DD 256
#define LL 64
#define EH 64
#define NG 3

typedef __attribute__((ext_vector_type(8))) short bs8;   // 8 bf16 (4 VGPR)
typedef __attribute__((ext_vector_type(4))) float f4;    // 4 f32

__device__ __forceinline__ short f2bf(float f) {
    __hip_bfloat16 h = __float2bfloat16(f);
    return *reinterpret_cast<short*>(&h);
}

// ---------------- helpers ----------------
__device__ __forceinline__ float blockReduceSum(float v, float* sRed) {
    int tid = threadIdx.x;
    __syncthreads();
    sRed[tid] = v;
    __syncthreads();
    for (int s = 128; s > 0; s >>= 1) {
        if (tid < s) sRed[tid] += sRed[tid + s];
        __syncthreads();
    }
    return sRed[0];
}

// ---------------- adj dtype probe: 0 = bool8, 1 = int32, 2 = float32 ----------------
__global__ __launch_bounds__(256) void k_detect(const unsigned char* __restrict__ adj,
                                                int* __restrict__ mode) {
    __shared__ int sOff, sBig;
    const int tid = threadIdx.x;
    if (tid == 0) { sOff = 0; sBig = 0; }
    __syncthreads();
    int off = 0, big = 0;
    #pragma unroll
    for (int k = 0; k < 4; ++k) {
        unsigned char v = adj[tid * 4 + k];
        if (v > 1) big = 1;
        if (k != 0 && v != 0) off = 1;
    }
    if (off) atomicOr(&sOff, 1);
    if (big) atomicOr(&sBig, 1);
    __syncthreads();
    if (tid == 0) mode[0] = sBig ? 2 : (sOff ? 0 : 1);
}

// ---------------- weight prep: transpose + f32->bf16 for update MLP ----------------
__global__ __launch_bounds__(256) void k_prep(
    const float* __restrict__ uw1, const float* __restrict__ uw2,
    unsigned short* __restrict__ w1t, unsigned short* __restrict__ w2t)
{
    const int blk = blockIdx.x, tid = threadIdx.x;
    const float* src; unsigned short* dst; int K, kt, dt;
    if (blk < 144) {
        int l = blk / 48, t = blk % 48; kt = t >> 2; dt = t & 3;
        src = uw1 + (size_t)l * 768 * 256; dst = w1t + (size_t)l * 256 * 768; K = 768;
    } else {
        int x = blk - 144; int l = x / 16, t = x % 16; kt = t >> 2; dt = t & 3;
        src = uw2 + (size_t)l * 65536; dst = w2t + (size_t)l * 65536; K = 256;
    }
    __shared__ float sT[64][65];
    #pragma unroll
    for (int q = 0; q < 16; ++q) {
        int idx = q * 256 + tid;
        int kk = idx >> 6, dd = idx & 63;
        sT[kk][dd] = src[(size_t)(kt * 64 + kk) * 256 + dt * 64 + dd];
    }
    __syncthreads();
    const int d = tid >> 2, kc = (tid & 3) * 16;
    unsigned short* drow = dst + (size_t)(dt * 64 + d) * K + kt * 64 + kc;
    #pragma unroll
    for (int i = 0; i < 16; ++i) drow[i] = (unsigned short)f2bf(sT[kc + i][d]);
}

// ---------------- gw2 prep: [3][64k][256d] f32 -> [3][256d][64k] bf16 ----------------
__global__ __launch_bounds__(256) void k_prepg(
    const float* __restrict__ gw2, unsigned short* __restrict__ g2t)
{
    const int blk = blockIdx.x, tid = threadIdx.x;
    const int l = blk >> 2, dt = blk & 3;
    const float* src = gw2 + (size_t)l * 64 * 256;
    unsigned short* dst = g2t + (size_t)l * 256 * 64;
    __shared__ float sT[64][65];
    #pragma unroll
    for (int q = 0; q < 16; ++q) {
        int idx = q * 256 + tid;
        int kk = idx >> 6, dd = idx & 63;
        sT[kk][dd] = src[(size_t)kk * 256 + dt * 64 + dd];
    }
    __syncthreads();
    const int d = tid >> 2, kc = (tid & 3) * 16;
    unsigned short* drow = dst + (size_t)(dt * 64 + d) * 64 + kc;
    #pragma unroll
    for (int i = 0; i < 16; ++i) drow[i] = (unsigned short)f2bf(sT[kc + i][d]);
}

// ---------------- node projection ----------------
__global__ __launch_bounds__(256) void k_nodeproj(
    const float* __restrict__ nf, const float* __restrict__ w,
    const float* __restrict__ bias, float* __restrict__ h)
{
    const int row = blockIdx.x, tid = threadIdx.x;
    __shared__ float sF[11];
    if (tid < 11) sF[tid] = nf[(size_t)row * 11 + tid];
    __syncthreads();
    float a = bias[tid];
    #pragma unroll
    for (int f = 0; f < 11; ++f) a += sF[f] * w[f * DD + tid];
    h[(size_t)row * DD + tid] = a;
}

// ---------------- layer-cost encoder ----------------
__global__ __launch_bounds__(256) void k_conv(
    const float* __restrict__ lc, const float* __restrict__ cw,
    const float* __restrict__ cb, float* __restrict__ conv)
{
    const int b = blockIdx.x, tid = threadIdx.x;
    __shared__ float sC[LL];
    if (tid < LL) sC[tid] = lc[b * LL + tid];
    __syncthreads();
    for (int idx = tid; idx < 992; idx += 256) {
        int c = idx / 31, t = idx % 31;
        float a = cb[c];
        #pragma unroll
        for (int k = 0; k < 4; ++k) a += sC[2 * t + k] * cw[c * 4 + k];
        conv[b * 992 + idx] = fmaxf(a, 0.f);
    }
}

__global__ __launch_bounds__(256) void k_lmm(
    const float* __restrict__ conv, const float* __restrict__ lpw,
    float* __restrict__ part)
{
    const int blk = blockIdx.x;
    const int b = blk >> 5, kseg = (blk >> 2) & 7, c4 = blk & 3;
    const int tid = threadIdx.x;
    const int d = tid & 63, ss = tid >> 6;
    __shared__ float sV[124];
    __shared__ float sP[4][64];
    if (tid < 124) sV[tid] = conv[b * 992 + kseg * 124 + tid];
    __syncthreads();
    float acc = 0.f;
    for (int k = ss; k < 124; k += 4)
        acc += sV[k] * lpw[(size_t)(kseg * 124 + k) * DD + c4 * 64 + d];
    sP[ss][d] = acc;
    __syncthreads();
    if (ss == 0)
        part[(b * 32 + kseg * 4 + c4) * 64 + d] = sP[0][d] + sP[1][d] + sP[2][d] + sP[3][d];
}

__global__ __launch_bounds__(256) void k_lred(
    const float* __restrict__ part, const float* __restrict__ lpb,
    float* __restrict__ le)
{
    const int b = blockIdx.x, tid = threadIdx.x;
    const int c4 = tid >> 6, d = tid & 63;
    float a = lpb[tid];
    #pragma unroll
    for (int kseg = 0; kseg < 8; ++kseg)
        a += part[(b * 32 + kseg * 4 + c4) * 64 + d];
    le[b * DD + tid] = a;
}

// ---------------- per-layer: preg = h @ gw1[:256] + gb1 ----------------
__global__ __launch_bounds__(256) void k_pregate(
    const float* __restrict__ h, const float* __restrict__ gw1,
    const float* __restrict__ gb1, float* __restrict__ preg)
{
    const int tid = threadIdx.x;
    const int row0 = blockIdx.x * 4;
    const int r = tid >> 6, t = tid & 63;
    __shared__ float sH[4][DD];
    for (int idx = tid; idx < 4 * DD; idx += 256)
        sH[idx >> 8][idx & 255] = h[(size_t)row0 * DD + idx];
    __syncthreads();
    float a = gb1[t];
    for (int k = 0; k < DD; ++k) a += sH[r][k] * gw1[k * EH + t];
    preg[(size_t)(row0 + r) * EH + t] = a;
}

// ---------------- fused edge-gate (MFMA) + masked aggregation ----------------
// PRE=1: gw2 pre-transposed bf16 in g2t (global, L2-resident) -> no LDS B staging.
template<int PRE>
__global__ __launch_bounds__(256) void k_edge(
    const float* __restrict__ h, const float* __restrict__ preg,
    const float* __restrict__ edge, const void* __restrict__ adj,
    const int* __restrict__ mode,
    const float* __restrict__ gw1,
    const float* __restrict__ gw2,
    const unsigned short* __restrict__ g2t,
    const float* __restrict__ gb2,
    float* __restrict__ agg_mean, float* __restrict__ agg_max)
{
    const int tid = threadIdx.x;
    const int bi = blockIdx.x;
    const int b = bi >> 7;
    const int lane = tid & 63, w = tid >> 6;
    const int lrow = lane >> 4, lcol = lane & 15;
    const int md = mode[0];

    __shared__ __align__(16) unsigned int sHid[4096];
    __shared__ __align__(16) unsigned short sB[PRE ? 16 : 16384];
    __shared__ float sWe[192];
    __shared__ float sE[384];
    __shared__ unsigned long long sMask[2];

    if (tid < 192) sWe[tid] = gw1[16384 + tid];
    const float* eB = edge + (size_t)bi * 384;
    for (int idx = tid; idx < 384; idx += 256) sE[idx] = eB[idx];
    if (tid < 128) {
        int mv;
        if (md == 1)      mv = ((const int*)adj)[(size_t)bi * NN_ + tid] != 0;
        else if (md == 2) mv = ((const float*)adj)[(size_t)bi * NN_ + tid] != 0.f;
        else              mv = ((const unsigned char*)adj)[(size_t)bi * NN_ + tid] != 0;
        unsigned long long bal = __ballot(mv);
        if ((tid & 63) == 0) sMask[tid >> 6] = bal;
    }
    __syncthreads();

    const float* pB = preg + (size_t)b * NN_ * EH;
    #pragma unroll
    for (int q = 0; q < 16; ++q) {
        int idx = q * 256 + tid;
        int j = idx >> 5, p = idx & 31;
        float2 pv = *(const float2*)(pB + j * EH + 2 * p);
        float e0 = sE[j * 3], e1 = sE[j * 3 + 1], e2 = sE[j * 3 + 2];
        int t0 = 2 * p, t1 = t0 + 1;
        float v0 = fmaxf(pv.x + e0 * sWe[t0] + e1 * sWe[64 + t0] + e2 * sWe[128 + t0], 0.f);
        float v1 = fmaxf(pv.y + e0 * sWe[t1] + e1 * sWe[64 + t1] + e2 * sWe[128 + t1], 0.f);
        unsigned int pk = (unsigned int)(unsigned short)f2bf(v0) |
                          ((unsigned int)(unsigned short)f2bf(v1) << 16);
        sHid[j * 32 + (p ^ ((j & 7) << 2))] = pk;
    }
    if constexpr (!PRE) {
        #pragma unroll
        for (int q = 0; q < 64; ++q) {
            int idx = q * 256 + tid;
            int k = idx >> 8, d = idx & 255;
            sB[(d * 64 + k) ^ ((d & 7) << 3)] = (unsigned short)f2bf(gw2[idx]);
        }
    }
    __syncthreads();

    const unsigned long long m0 = sMask[0], m1 = sMask[1];
    const float cntf = (float)(__popcll(m0) + __popcll(m1));

    bs8 bfr[4][2];
    float bg[4];
    #pragma unroll
    for (int nt = 0; nt < 4; ++nt) {
        int d = w * 64 + nt * 16 + lcol;
        bg[nt] = gb2[d];
        #pragma unroll
        for (int ks = 0; ks < 2; ++ks) {
            int k0 = ks * 32 + lrow * 8;
            if constexpr (PRE)
                bfr[nt][ks] = *(const bs8*)(g2t + (size_t)d * 64 + k0);
            else
                bfr[nt][ks] = *(const bs8*)(sB + ((d * 64 + k0) ^ ((d & 7) << 3)));
        }
    }

    const float* hB = h + (size_t)b * NN_ * DD;
    float vs[4] = {0.f, 0.f, 0.f, 0.f};
    float vm[4] = {-INFINITY, -INFINITY, -INFINITY, -INFINITY};

    #pragma unroll
    for (int pp = 0; pp < 2; ++pp) {
        f4 acc[4][4] = {};
        #pragma unroll
        for (int ks = 0; ks < 2; ++ks) {
            bs8 afr[4];
            #pragma unroll
            for (int m = 0; m < 4; ++m) {
                int j = pp * 64 + m * 16 + lcol;
                int k0 = ks * 32 + lrow * 8;
                afr[m] = *(const bs8*)(sHid + (j * 32 + ((k0 >> 1) ^ ((j & 7) << 2))));
            }
            #pragma unroll
            for (int m = 0; m < 4; ++m)
                #pragma unroll
                for (int nt = 0; nt < 4; ++nt)
                    acc[m][nt] = __builtin_amdgcn_mfma_f32_16x16x32_bf16(
                        afr[m], bfr[nt][ks], acc[m][nt], 0, 0, 0);
        }
        const unsigned long long mw = pp ? m1 : m0;
        #pragma unroll
        for (int m = 0; m < 4; ++m) {
            #pragma unroll
            for (int nt = 0; nt < 4; ++nt) {
                int dnt = w * 64 + nt * 16 + lcol;
                #pragma unroll
                for (int r = 0; r < 4; ++r) {
                    int bit = m * 16 + lrow * 4 + r;
                    float x = acc[m][nt][r] + bg[nt];
                    float g = __builtin_amdgcn_rcpf(1.0f + __expf(-x));
                    float msg = g * hB[(pp * 64 + bit) * DD + dnt];
                    int on = (int)((mw >> bit) & 1ULL);
                    vs[nt] += on ? msg : 0.f;
                    vm[nt] = fmaxf(vm[nt], on ? msg : -INFINITY);
                }
            }
        }
    }

    #pragma unroll
    for (int nt = 0; nt < 4; ++nt) {
        float s = vs[nt];
        s += __shfl_xor(s, 16); s += __shfl_xor(s, 32);
        vs[nt] = s;
        float m = vm[nt];
        m = fmaxf(m, __shfl_xor(m, 16)); m = fmaxf(m, __shfl_xor(m, 32));
        vm[nt] = m;
    }
    const int g = lrow;
    float ssel = (g == 0) ? vs[0] : (g == 1) ? vs[1] : (g == 2) ? vs[2] : vs[3];
    float msel = (g == 0) ? vm[0] : (g == 1) ? vm[1] : (g == 2) ? vm[2] : vm[3];
    const int d = w * 64 + lane;
    agg_mean[(size_t)bi * DD + d] = ssel / fmaxf(cntf, 1.f);
    agg_max[(size_t)bi * DD + d] = (cntf > 0.f) ? msel : 0.f;
}

// ---------------- MFMA update MLP + residual + LN ----------------
__global__ __launch_bounds__(256) void k_upd(
    const float* __restrict__ h, const float* __restrict__ amean,
    const float* __restrict__ amax,
    const unsigned short* __restrict__ w1t,
    const float* __restrict__ ub1,
    const unsigned short* __restrict__ w2t,
    const float* __restrict__ ub2,
    const float* __restrict__ lng, const float* __restrict__ lnb,
    float* __restrict__ hout, float* __restrict__ out2)
{
    const int tid = threadIdx.x;
    const int row0 = blockIdx.x * 4;
    const int lane = tid & 63, w = tid >> 6;
    const int lcol = lane & 15, lrow = lane >> 4;

    __shared__ __align__(16) unsigned int sX32[16 * 384];
    __shared__ __align__(16) unsigned short sH16[16 * 256];
    __shared__ float sRes[4][256];
    __shared__ float sOut[4][256];

    {
        const int j = w;
        const float* hR = h + (size_t)(row0 + j) * DD;
        const float* mR = amean + (size_t)(row0 + j) * DD;
        const float* xR = amax + (size_t)(row0 + j) * DD;
        #pragma unroll
        for (int q = 0; q < 6; ++q) {
            int p = lane + q * 64;
            int k = 2 * p;
            float2 v;
            if (k < 256)      { v = *(const float2*)(hR + k); sRes[j][k] = v.x; sRes[j][k + 1] = v.y; }
            else if (k < 512)   v = *(const float2*)(mR + (k - 256));
            else                v = *(const float2*)(xR + (k - 512));
            unsigned int pk = (unsigned int)(unsigned short)f2bf(v.x) |
                              ((unsigned int)(unsigned short)f2bf(v.y) << 16);
            sX32[j * 384 + (p ^ (j << 2))] = pk;
        }
    }
    __syncthreads();

    const char* sXb = (const char*)sX32;
    const unsigned short* w1r = w1t + (size_t)(w * 64 + lcol) * 768;
    f4 a0 = {0.f, 0.f, 0.f, 0.f}, a1 = a0, a2 = a0, a3 = a0;
    #pragma unroll 4
    for (int ks = 0; ks < 24; ++ks) {
        int k0 = ks * 32 + lrow * 8;
        bs8 av = *(const bs8*)(sXb + lcol * 1536 + ((((k0 >> 3) ^ (lcol & 7))) << 4));
        bs8 b0 = *(const bs8*)(w1r + k0);
        bs8 b1 = *(const bs8*)(w1r + 16 * 768 + k0);
        bs8 b2 = *(const bs8*)(w1r + 32 * 768 + k0);
        bs8 b3 = *(const bs8*)(w1r + 48 * 768 + k0);
        a0 = __builtin_amdgcn_mfma_f32_16x16x32_bf16(av, b0, a0, 0, 0, 0);
        a1 = __builtin_amdgcn_mfma_f32_16x16x32_bf16(av, b1, a1, 0, 0, 0);
        a2 = __builtin_amdgcn_mfma_f32_16x16x32_bf16(av, b2, a2, 0, 0, 0);
        a3 = __builtin_amdgcn_mfma_f32_16x16x32_bf16(av, b3, a3, 0, 0, 0);
    }
    if (lrow == 0) {
        #pragma unroll
        for (int nt = 0; nt < 4; ++nt) {
            int d = w * 64 + nt * 16 + lcol;
            float bb = ub1[d];
            f4 A = (nt == 0) ? a0 : (nt == 1) ? a1 : (nt == 2) ? a2 : a3;
            #pragma unroll
            for (int r = 0; r < 4; ++r) {
                float hv = fmaxf(A[r] + bb, 0.f);
                sH16[r * 256 + (d ^ (r << 3))] = (unsigned short)f2bf(hv);
            }
        }
    }
    __syncthreads();

    const unsigned short* w2r = w2t + (size_t)(w * 64 + lcol) * 256;
    f4 c0 = {0.f, 0.f, 0.f, 0.f}, c1 = c0, c2 = c0, c3 = c0;
    #pragma unroll
    for (int ks = 0; ks < 8; ++ks) {
        int k0 = ks * 32 + lrow * 8;
        bs8 av = *(const bs8*)((const char*)sH16 + lcol * 512 + ((((k0 >> 3) ^ (lcol & 7))) << 4));
        bs8 b0 = *(const bs8*)(w2r + k0);
        bs8 b1 = *(const bs8*)(w2r + 16 * 256 + k0);
        bs8 b2 = *(const bs8*)(w2r + 32 * 256 + k0);
        bs8 b3 = *(const bs8*)(w2r + 48 * 256 + k0);
        c0 = __builtin_amdgcn_mfma_f32_16x16x32_bf16(av, b0, c0, 0, 0, 0);
        c1 = __builtin_amdgcn_mfma_f32_16x16x32_bf16(av, b1, c1, 0, 0, 0);
        c2 = __builtin_amdgcn_mfma_f32_16x16x32_bf16(av, b2, c2, 0, 0, 0);
        c3 = __builtin_amdgcn_mfma_f32_16x16x32_bf16(av, b3, c3, 0, 0, 0);
    }
    if (lrow == 0) {
        #pragma unroll
        for (int nt = 0; nt < 4; ++nt) {
            int d = w * 64 + nt * 16 + lcol;
            float bb = ub2[d];
            f4 C = (nt == 0) ? c0 : (nt == 1) ? c1 : (nt == 2) ? c2 : c3;
            #pragma unroll
            for (int r = 0; r < 4; ++r)
                sOut[r][d] = C[r] + bb + sRes[r][d];
        }
    }
    __syncthreads();

    float xv[4], s = 0.f;
    #pragma unroll
    for (int q = 0; q < 4; ++q) { xv[q] = sOut[w][lane + 64 * q]; s += xv[q]; }
    #pragma unroll
    for (int off = 1; off < 64; off <<= 1) s += __shfl_xor(s, off);
    const float mu = s * (1.f / DD);
    float s2 = 0.f;
    #pragma unroll
    for (int q = 0; q < 4; ++q) { float d = xv[q] - mu; s2 += d * d; }
    #pragma unroll
    for (int off = 1; off < 64; off <<= 1) s2 += __shfl_xor(s2, off);
    const float inv = rsqrtf(s2 * (1.f / DD) + 1e-5f);
    #pragma unroll
    for (int q = 0; q < 4; ++q) {
        int c = lane + 64 * q;
        float res = (xv[q] - mu) * inv * lng[c] + lnb[c];
        hout[(size_t)(row0 + w) * DD + c] = res;
        if (out2) out2[(size_t)(row0 + w) * DD + c] = res;
    }
}

// ---------------- fallback f32 update (ws too small) ----------------
__global__ __launch_bounds__(256) void k_update(
    const float* __restrict__ agg_mean, const float* __restrict__ agg_max,
    const float* __restrict__ uw1, const float* __restrict__ ub1,
    const float* __restrict__ uw2, const float* __restrict__ ub2,
    const float* __restrict__ lng, const float* __restrict__ lnb,
    float* __restrict__ h, float* __restrict__ out2)
{
    const int tid = threadIdx.x;
    const int row0 = blockIdx.x * 4;
    __shared__ float sUi[4][3 * DD];
    __shared__ float sHid[4][DD];
    __shared__ float sRed[256];
    for (int idx = tid; idx < 4 * 3 * DD; idx += 256) {
        int r = idx / (3 * DD), k = idx % (3 * DD);
        int row = row0 + r;
        float v;
        if (k < DD)            v = h[(size_t)row * DD + k];
        else if (k < 2 * DD)   v = agg_mean[(size_t)row * DD + (k - DD)];
        else                   v = agg_max[(size_t)row * DD + (k - 2 * DD)];
        sUi[r][k] = v;
    }
    __syncthreads();
    float b1 = ub1[tid];
    float a0 = b1, a1 = b1, a2 = b1, a3 = b1;
    for (int k = 0; k < 3 * DD; ++k) {
        float wv = uw1[k * DD + tid];
        a0 += sUi[0][k] * wv; a1 += sUi[1][k] * wv;
        a2 += sUi[2][k] * wv; a3 += sUi[3][k] * wv;
    }
    sHid[0][tid] = fmaxf(a0, 0.f); sHid[1][tid] = fmaxf(a1, 0.f);
    sHid[2][tid] = fmaxf(a2, 0.f); sHid[3][tid] = fmaxf(a3, 0.f);
    __syncthreads();
    float b2 = ub2[tid];
    float x[4] = {b2, b2, b2, b2};
    for (int k = 0; k < DD; ++k) {
        float wv = uw2[k * DD + tid];
        x[0] += sHid[0][k] * wv; x[1] += sHid[1][k] * wv;
        x[2] += sHid[2][k] * wv; x[3] += sHid[3][k] * wv;
    }
    #pragma unroll
    for (int r = 0; r < 4; ++r) x[r] += h[(size_t)(row0 + r) * DD + tid];
    const float g = lng[tid], be = lnb[tid];
    for (int r = 0; r < 4; ++r) {
        float mu = blockReduceSum(x[r], sRed) * (1.f / DD);
        float dc = x[r] - mu;
        float var = blockReduceSum(dc * dc, sRed) * (1.f / DD);
        float res = dc * rsqrtf(var + 1e-5f) * g + be;
        h[(size_t)(row0 + r) * DD + tid] = res;
        if (out2) out2[(size_t)(row0 + r) * DD + tid] = res;
    }
}

// ---------------- graph embed ----------------
__global__ __launch_bounds__(256) void k_gembed(
    const float* __restrict__ nf, const float* __restrict__ h, float* __restrict__ ge)
{
    const int b = blockIdx.x, tid = threadIdx.x;
    __shared__ float sW[NN_];
    __shared__ float sRed[256];
    if (tid < NN_) {
        const float* p = nf + ((size_t)b * NN_ + tid) * 11;
        sW[tid] = p[0] * p[7];
    }
    __syncthreads();
    float part = (tid < NN_) ? sW[tid] : 0.f;
    float wsum = blockReduceSum(part, sRed);
    float acc = 0.f;
    for (int n = 0; n < NN_; ++n) acc += sW[n] * h[((size_t)b * NN_ + n) * DD + tid];
    ge[b * DD + tid] = acc / fmaxf(wsum, 1e-8f);
}

// ---------------- head GEMMs, all batches per weight load ----------------
// grid 96: blk = m*32 + kseg*4 + c4; 256 thr = 64 d x 4 ksub
__global__ __launch_bounds__(256) void k_hmm(
    const float* __restrict__ ge, const float* __restrict__ le,
    const float* __restrict__ gd,
    const float* __restrict__ qw, const float* __restrict__ sw1,
    const float* __restrict__ vw1, float* __restrict__ part)
{
    const int blk = blockIdx.x;
    const int m = blk >> 5, kseg = (blk >> 2) & 7, c4 = blk & 3;
    const int tid = threadIdx.x;
    const int d = tid & 63, ks = tid >> 6;
    const int K = (m == 1) ? 258 : 514;
    const int kc = (m == 1) ? 33 : 65;
    const int k0 = kseg * kc;
    const int klen = min(k0 + kc, K) - k0;
    __shared__ float sX[8 * 66];
    __shared__ float sP[4][8][64];
    for (int idx = tid; idx < 8 * kc; idx += 256) {
        int b = idx / kc, kk = idx % kc, k = k0 + kk;
        float v = 0.f;
        if (k < K) {
            if (m == 1) v = (k < 256) ? ge[b * DD + k] : gd[b * 2 + (k - 256)];
            else        v = (k < 256) ? ge[b * DD + k]
                          : (k < 512) ? le[b * DD + (k - 256)]
                                      : gd[b * 2 + (k - 512)];
        }
        sX[b * 66 + kk] = v;
    }
    __syncthreads();
    const float* W = (m == 0) ? qw : (m == 1) ? sw1 : vw1;
    const int dg = c4 * 64 + d;
    float acc[8] = {0.f, 0.f, 0.f, 0.f, 0.f, 0.f, 0.f, 0.f};
    for (int kk = ks; kk < klen; kk += 4) {
        float wv = W[(size_t)(k0 + kk) * DD + dg];
        #pragma unroll
        for (int b = 0; b < 8; ++b) acc[b] += sX[b * 66 + kk] * wv;
    }
    #pragma unroll
    for (int b = 0; b < 8; ++b) sP[ks][b][d] = acc[b];
    __syncthreads();
    for (int idx = tid; idx < 8 * 64; idx += 256) {
        int b = idx >> 6, dd = idx & 63;
        float sum = sP[0][b][dd] + sP[1][b][dd] + sP[2][b][dd] + sP[3][b][dd];
        part[((m * 8 + kseg) * 8 + b) * DD + c4 * 64 + dd] = sum;
    }
}

// ---------------- head finalize: reduce ksegs, relu, stop/value dots ----------------
__global__ __launch_bounds__(256) void k_hfin(
    const float* __restrict__ part,
    const float* __restrict__ qb, const float* __restrict__ sb1,
    const float* __restrict__ vb1,
    const float* __restrict__ sw2, const float* __restrict__ sb2,
    const float* __restrict__ vw2, const float* __restrict__ vb2,
    float* __restrict__ query, float* __restrict__ out)
{
    const int b = blockIdx.x, tid = threadIdx.x;
    __shared__ float sRed[256];
    float q = qb[tid], s = sb1[tid], v = vb1[tid];
    #pragma unroll
    for (int kseg = 0; kseg < 8; ++kseg) {
        q += part[((0 * 8 + kseg) * 8 + b) * DD + tid];
        s += part[((1 * 8 + kseg) * 8 + b) * DD + tid];
        v += part[((2 * 8 + kseg) * 8 + b) * DD + tid];
    }
    query[b * DD + tid] = q;
    s = fmaxf(s, 0.f); v = fmaxf(v, 0.f);
    float stop = blockReduceSum(s * sw2[tid], sRed);
    float val  = blockReduceSum(v * vw2[tid], sRed);
    if (tid == 0) {
        out[b * 129 + 128] = stop + sb2[0];
        out[1032 + b] = val + vb2[0];
    }
}

// ---------------- device scores ----------------
__global__ __launch_bounds__(256) void k_scores(
    const float* __restrict__ h, const float* __restrict__ kw,
    const float* __restrict__ kb, const float* __restrict__ query,
    float* __restrict__ out)
{
    const int tid = threadIdx.x;
    const int row0 = blockIdx.x * 4;
    __shared__ float sH[4][DD];
    __shared__ float sRed[256];
    for (int idx = tid; idx < 4 * DD; idx += 256)
        sH[idx >> 8][idx & 255] = h[(size_t)row0 * DD + idx];
    __syncthreads();
    float bb = kb[tid];
    float a0 = bb, a1 = bb, a2 = bb, a3 = bb;
    for (int k = 0; k < DD; ++k) {
        float wv = kw[k * DD + tid];
        a0 += sH[0][k] * wv; a1 += sH[1][k] * wv;
        a2 += sH[2][k] * wv; a3 += sH[3][k] * wv;
    }
    const int b = row0 >> 7;
    const float q = query[b * DD + tid];
    float s0 = blockReduceSum(a0 * q, sRed);
    float s1 = blockReduceSum(a1 * q, sRed);
    float s2 = blockReduceSum(a2 * q, sRed);
    float s3 = blockReduceSum(a3 * q, sRed);
    if (tid == 0) {
        int n0 = row0 & (NN_ - 1);
        out[b * 129 + n0 + 0] = s0 * 0.0625f;
        out[b * 129 + n0 + 1] = s1 * 0.0625f;
        out[b * 129 + n0 + 2] = s2 * 0.0625f;
        out[b * 129 + n0 + 3] = s3 * 0.0625f;
    }
}

extern "C" void kernel_launch(void* const* d_in, const int* in_sizes, int n_in,
                              void* d_out, int out_size, void* d_ws, size_t ws_size,
                              hipStream_t stream) {
    (void)in_sizes; (void)n_in; (void)out_size;
    const float* nf  = (const float*)d_in[0];
    const float* ef  = (const float*)d_in[1];
    const void*  adj = d_in[2];
    const float* lc  = (const float*)d_in[3];
    const float* gd  = (const float*)d_in[4];
    const float* pnw = (const float*)d_in[5];
    const float* pnb = (const float*)d_in[6];
    const float* gw1 = (const float*)d_in[7];
    const float* gb1 = (const float*)d_in[8];
    const float* gw2 = (const float*)d_in[9];
    const float* gb2 = (const float*)d_in[10];
    const float* uw1 = (const float*)d_in[11];
    const float* ub1 = (const float*)d_in[12];
    const float* uw2 = (const float*)d_in[13];
    const float* ub2 = (const float*)d_in[14];
    const float* lng = (const float*)d_in[15];
    const float* lnb = (const float*)d_in[16];
    const float* cw  = (const float*)d_in[17];
    const float* cb  = (const float*)d_in[18];
    const float* lpw = (const float*)d_in[19];
    const float* lpb = (const float*)d_in[20];
    const float* qw  = (const float*)d_in[21];
    const float* qb  = (const float*)d_in[22];
    const float* kw  = (const float*)d_in[23];
    const float* kb  = (const float*)d_in[24];
    const float* sw1 = (const float*)d_in[25];
    const float* sb1 = (const float*)d_in[26];
    const float* sw2 = (const float*)d_in[27];
    const float* sb2 = (const float*)d_in[28];
    const float* vw1 = (const float*)d_in[29];
    const float* vb1 = (const float*)d_in[30];
    const float* vw2 = (const float*)d_in[31];
    const float* vb2 = (const float*)d_in[32];

    float* ws = (float*)d_ws;
    float* h     = ws;                         // 262144
    float* preg  = ws + 262144;                // 65536
    float* amean = ws + 327680;                // 262144 (lmm partials / head partials)
    float* amax  = ws + 589824;                // 262144 (conv buffer early)
    float* le    = ws + 851968;                // 2048
    float* ge    = ws + 854016;                // 2048
    float* query = ws + 856064;                // 2048
    int*   mode  = (int*)(ws + 862208);        // 1 (pad to 862212)
    unsigned short* uw1t = (unsigned short*)(ws + 862212);   // 589824 bf16
    unsigned short* uw2t = (unsigned short*)(ws + 1157124);  // 196608 bf16
    unsigned short* g2t  = (unsigned short*)(ws + 1255428);  // 49152 bf16
    const size_t NEED = (size_t)1280004 * 4;
    const bool pre = ws_size >= NEED;
    float* conv  = amax;
    float* lpart = amean;
    float* hpart = amean;
    float* out   = (float*)d_out;

    k_detect<<<1, 256, 0, stream>>>((const unsigned char*)adj, mode);
    if (pre) {
        k_prep<<<192, 256, 0, stream>>>(uw1, uw2, uw1t, uw2t);
        k_prepg<<<12, 256, 0, stream>>>(gw2, g2t);
    }
    k_nodeproj<<<BB * NN_, 256, 0, stream>>>(nf, pnw, pnb, h);
    k_conv<<<BB, 256, 0, stream>>>(lc, cw, cb, conv);
    k_lmm<<<256, 256, 0, stream>>>(conv, lpw, lpart);
    k_lred<<<BB, 256, 0, stream>>>(lpart, lpb, le);
    for (int i = 0; i < NG; ++i) {
        const float* gw1i = gw1 + (size_t)i * 259 * EH;
        float* out2sel = (i == NG - 1) ? (out + 1040) : (float*)nullptr;
        k_pregate<<<BB * NN_ / 4, 256, 0, stream>>>(h, gw1i, gb1 + i * EH, preg);
        if (pre) {
            k_edge<1><<<BB * NN_, 256, 0, stream>>>(h, preg, ef, adj, mode, gw1i,
                                                    gw2 + (size_t)i * EH * DD,
                                                    g2t + (size_t)i * 16384,
                                                    gb2 + i * DD, amean, amax);
            k_upd<<<BB * NN_ / 4, 256, 0, stream>>>(h, amean, amax,
                                                    uw1t + (size_t)i * 196608, ub1 + i * DD,
                                                    uw2t + (size_t)i * 65536, ub2 + i * DD,
                                                    lng + i * DD, lnb + i * DD, h, out2sel);
        } else {
            k_edge<0><<<BB * NN_, 256, 0, stream>>>(h, preg, ef, adj, mode, gw1i,
                                                    gw2 + (size_t)i * EH * DD,
                                                    (const unsigned short*)nullptr,
                                                    gb2 + i * DD, amean, amax);
            k_update<<<BB * NN_ / 4, 256, 0, stream>>>(amean, amax,
                                                       uw1 + (size_t)i * 3 * DD * DD, ub1 + i * DD,
                                                       uw2 + (size_t)i * DD * DD, ub2 + i * DD,
                                                       lng + i * DD, lnb + i * DD, h, out2sel);
        }
    }
    k_gembed<<<BB, 256, 0, stream>>>(nf, h, ge);
    k_hmm<<<96, 256, 0, stream>>>(ge, le, gd, qw, sw1, vw1, hpart);
    k_hfin<<<BB, 256, 0, stream>>>(hpart, qb, sb1, vb1, sw2, sb2, vw2, vb2, query, out);
    k_scores<<<BB * NN_ / 4, 256, 0, stream>>>(h, kw, kb, query, out);
}

// Round 7
// 198.785 us; speedup vs baseline: 2.9137x; 1.0888x over previous
//
#include <hip/hip_runtime.h>
#include <hip/hip_bf16.h>
#include <math.h>

// Problem constants
#define BB 8
#define NN_ 128
#define DD 256
#define LL 64
#define EH 64
#define NG 3

typedef __attribute__((ext_vector_type(8))) short bs8;   // 8 bf16 (4 VGPR)
typedef __attribute__((ext_vector_type(4))) float f4;    // 4 f32

__device__ __forceinline__ short f2bf(float f) {
    __hip_bfloat16 h = __float2bfloat16(f);
    return *reinterpret_cast<short*>(&h);
}

__device__ __forceinline__ bs8 cvt8(const float* __restrict__ p) {
    bs8 r;
    #pragma unroll
    for (int i = 0; i < 8; ++i) r[i] = f2bf(p[i]);
    return r;
}

__device__ __forceinline__ float blockReduceSum(float v, float* sRed) {
    int tid = threadIdx.x;
    __syncthreads();
    sRed[tid] = v;
    __syncthreads();
    for (int s = 128; s > 0; s >>= 1) {
        if (tid < s) sRed[tid] += sRed[tid + s];
        __syncthreads();
    }
    return sRed[0];
}

// ---------------- unified prep: all weight transposes (f32->bf16) + adj dtype probe ----------------
// blocks 0..143 uw1, 144..191 uw2, 192..203 gw2, 204..215 gw1[:256], 216..231 kw, 232 detect
__global__ __launch_bounds__(256) void k_prep(
    const float* __restrict__ uw1, const float* __restrict__ uw2,
    const float* __restrict__ gw2, const float* __restrict__ gw1,
    const float* __restrict__ kw, const unsigned char* __restrict__ adj,
    unsigned short* __restrict__ w1t, unsigned short* __restrict__ w2t,
    unsigned short* __restrict__ g2t, unsigned short* __restrict__ g1t,
    unsigned short* __restrict__ kwt, int* __restrict__ mode)
{
    const int blk = blockIdx.x, tid = threadIdx.x;
    if (blk == 232) {   // adj dtype probe: 0 = bool8, 1 = int32, 2 = float32
        __shared__ int sOff, sBig;
        if (tid == 0) { sOff = 0; sBig = 0; }
        __syncthreads();
        int off = 0, big = 0;
        #pragma unroll
        for (int k = 0; k < 4; ++k) {
            unsigned char v = adj[tid * 4 + k];
            if (v > 1) big = 1;
            if (k != 0 && v != 0) off = 1;
        }
        if (off) atomicOr(&sOff, 1);
        if (big) atomicOr(&sBig, 1);
        __syncthreads();
        if (tid == 0) mode[0] = sBig ? 2 : (sOff ? 0 : 1);
        return;
    }
    const float* src; unsigned short* dst; int K, kt, dt, srcw = 256;
    if (blk < 144)      { int l = blk / 48, t = blk % 48; kt = t >> 2; dt = t & 3;
                          src = uw1 + (size_t)l * 196608; dst = w1t + (size_t)l * 196608; K = 768; }
    else if (blk < 192) { int x = blk - 144, l = x / 16, t = x % 16; kt = t >> 2; dt = t & 3;
                          src = uw2 + (size_t)l * 65536; dst = w2t + (size_t)l * 65536; K = 256; }
    else if (blk < 204) { int x = blk - 192, l = x >> 2; kt = 0; dt = x & 3;
                          src = gw2 + (size_t)l * 16384; dst = g2t + (size_t)l * 16384; K = 64; }
    else if (blk < 216) { int x = blk - 204, l = x >> 2; kt = x & 3; dt = 0; srcw = 64;
                          src = gw1 + (size_t)l * 16576; dst = g1t + (size_t)l * 16384; K = 256; }
    else                { int x = blk - 216; kt = x >> 2; dt = x & 3;
                          src = kw; dst = kwt; K = 256; }
    __shared__ float sT[64][65];
    #pragma unroll
    for (int q = 0; q < 16; ++q) {
        int idx = q * 256 + tid, kk = idx >> 6, dd = idx & 63;
        sT[kk][dd] = src[(size_t)(kt * 64 + kk) * srcw + dt * 64 + dd];
    }
    __syncthreads();
    const int d = tid >> 2, kc = (tid & 3) * 16;
    unsigned short* drow = dst + (size_t)(dt * 64 + d) * K + kt * 64 + kc;
    #pragma unroll
    for (int i = 0; i < 16; ++i) drow[i] = (unsigned short)f2bf(sT[kc + i][d]);
}

// ---------------- node projection ----------------
__global__ __launch_bounds__(256) void k_nodeproj(
    const float* __restrict__ nf, const float* __restrict__ w,
    const float* __restrict__ bias, float* __restrict__ h)
{
    const int row = blockIdx.x, tid = threadIdx.x;
    __shared__ float sF[11];
    if (tid < 11) sF[tid] = nf[(size_t)row * 11 + tid];
    __syncthreads();
    float a = bias[tid];
    #pragma unroll
    for (int f = 0; f < 11; ++f) a += sF[f] * w[f * DD + tid];
    h[(size_t)row * DD + tid] = a;
}

// ---------------- layer-cost encoder: conv fused into split-k GEMM ----------------
__global__ __launch_bounds__(256) void k_lmm(
    const float* __restrict__ lc, const float* __restrict__ cw,
    const float* __restrict__ cb, const float* __restrict__ lpw,
    float* __restrict__ part)
{
    const int blk = blockIdx.x;
    const int b = blk >> 5, kseg = (blk >> 2) & 7, c4 = blk & 3;
    const int tid = threadIdx.x;
    const int d = tid & 63, ss = tid >> 6;
    __shared__ float sC[LL];
    __shared__ float sV[124];
    __shared__ float sP[4][64];
    if (tid < LL) sC[tid] = lc[b * LL + tid];
    __syncthreads();
    if (tid < 124) {
        int idx = kseg * 124 + tid;
        int c = idx / 31, t = idx - c * 31;
        float a = cb[c];
        #pragma unroll
        for (int k = 0; k < 4; ++k) a += sC[2 * t + k] * cw[c * 4 + k];
        sV[tid] = fmaxf(a, 0.f);
    }
    __syncthreads();
    float acc = 0.f;
    for (int k = ss; k < 124; k += 4)
        acc += sV[k] * lpw[(size_t)(kseg * 124 + k) * DD + c4 * 64 + d];
    sP[ss][d] = acc;
    __syncthreads();
    if (ss == 0)
        part[(b * 32 + kseg * 4 + c4) * 64 + d] = sP[0][d] + sP[1][d] + sP[2][d] + sP[3][d];
}

// ---------------- MFMA pregate: preg = h @ gw1[:256] + gb1 (16 rows/block) ----------------
__global__ __launch_bounds__(256) void k_pregate(
    const float* __restrict__ h, const unsigned short* __restrict__ g1t,
    const float* __restrict__ gb1, float* __restrict__ preg)
{
    const int tid = threadIdx.x, blk = blockIdx.x;
    const int row0 = blk * 16;
    const int lane = tid & 63, w = tid >> 6;
    const int lcol = lane & 15, lrow = lane >> 4;
    const float* aR = h + (size_t)(row0 + lcol) * DD;
    const unsigned short* bR = g1t + (size_t)(w * 16 + lcol) * 256;
    f4 acc = {0.f, 0.f, 0.f, 0.f};
    #pragma unroll
    for (int ks = 0; ks < 8; ++ks) {
        int k0 = ks * 32 + lrow * 8;
        bs8 av = cvt8(aR + k0);
        bs8 bv = *(const bs8*)(bR + k0);
        acc = __builtin_amdgcn_mfma_f32_16x16x32_bf16(av, bv, acc, 0, 0, 0);
    }
    const float gb = gb1[w * 16 + lcol];
    #pragma unroll
    for (int r = 0; r < 4; ++r)
        preg[(size_t)(row0 + lrow * 4 + r) * EH + w * 16 + lcol] = acc[r] + gb;
}

// ---------------- fused edge-gate (MFMA) + masked aggregation ----------------
__global__ __launch_bounds__(256) void k_edge(
    const float* __restrict__ h, const float* __restrict__ preg,
    const float* __restrict__ edge, const void* __restrict__ adj,
    const int* __restrict__ mode,
    const float* __restrict__ gw1,
    const unsigned short* __restrict__ g2t,
    const float* __restrict__ gb2,
    float* __restrict__ agg_mean, float* __restrict__ agg_max)
{
    const int tid = threadIdx.x;
    const int bi = blockIdx.x;
    const int b = bi >> 7;
    const int lane = tid & 63, w = tid >> 6;
    const int lrow = lane >> 4, lcol = lane & 15;
    const int md = mode[0];

    __shared__ __align__(16) unsigned int sHid[4096];
    __shared__ float sWe[192];
    __shared__ float sE[384];
    __shared__ unsigned long long sMask[2];

    if (tid < 192) sWe[tid] = gw1[16384 + tid];
    const float* eB = edge + (size_t)bi * 384;
    for (int idx = tid; idx < 384; idx += 256) sE[idx] = eB[idx];
    if (tid < 128) {
        int mv;
        if (md == 1)      mv = ((const int*)adj)[(size_t)bi * NN_ + tid] != 0;
        else if (md == 2) mv = ((const float*)adj)[(size_t)bi * NN_ + tid] != 0.f;
        else              mv = ((const unsigned char*)adj)[(size_t)bi * NN_ + tid] != 0;
        unsigned long long bal = __ballot(mv);
        if ((tid & 63) == 0) sMask[tid >> 6] = bal;
    }
    __syncthreads();

    const float* pB = preg + (size_t)b * NN_ * EH;
    #pragma unroll
    for (int q = 0; q < 16; ++q) {
        int idx = q * 256 + tid;
        int j = idx >> 5, p = idx & 31;
        float2 pv = *(const float2*)(pB + j * EH + 2 * p);
        float e0 = sE[j * 3], e1 = sE[j * 3 + 1], e2 = sE[j * 3 + 2];
        int t0 = 2 * p, t1 = t0 + 1;
        float v0 = fmaxf(pv.x + e0 * sWe[t0] + e1 * sWe[64 + t0] + e2 * sWe[128 + t0], 0.f);
        float v1 = fmaxf(pv.y + e0 * sWe[t1] + e1 * sWe[64 + t1] + e2 * sWe[128 + t1], 0.f);
        unsigned int pk = (unsigned int)(unsigned short)f2bf(v0) |
                          ((unsigned int)(unsigned short)f2bf(v1) << 16);
        sHid[j * 32 + (p ^ ((j & 7) << 2))] = pk;
    }
    __syncthreads();

    const unsigned long long m0 = sMask[0], m1 = sMask[1];
    const float cntf = (float)(__popcll(m0) + __popcll(m1));

    bs8 bfr[4][2];
    float bg[4];
    #pragma unroll
    for (int nt = 0; nt < 4; ++nt) {
        int d = w * 64 + nt * 16 + lcol;
        bg[nt] = gb2[d];
        #pragma unroll
        for (int ks = 0; ks < 2; ++ks) {
            int k0 = ks * 32 + lrow * 8;
            bfr[nt][ks] = *(const bs8*)(g2t + (size_t)d * 64 + k0);
        }
    }

    const float* hB = h + (size_t)b * NN_ * DD;
    float vs[4] = {0.f, 0.f, 0.f, 0.f};
    float vm[4] = {-INFINITY, -INFINITY, -INFINITY, -INFINITY};

    #pragma unroll
    for (int pp = 0; pp < 2; ++pp) {
        f4 acc[4][4] = {};
        #pragma unroll
        for (int ks = 0; ks < 2; ++ks) {
            bs8 afr[4];
            #pragma unroll
            for (int m = 0; m < 4; ++m) {
                int j = pp * 64 + m * 16 + lcol;
                int k0 = ks * 32 + lrow * 8;
                afr[m] = *(const bs8*)(sHid + (j * 32 + ((k0 >> 1) ^ ((j & 7) << 2))));
            }
            #pragma unroll
            for (int m = 0; m < 4; ++m)
                #pragma unroll
                for (int nt = 0; nt < 4; ++nt)
                    acc[m][nt] = __builtin_amdgcn_mfma_f32_16x16x32_bf16(
                        afr[m], bfr[nt][ks], acc[m][nt], 0, 0, 0);
        }
        const unsigned long long mw = pp ? m1 : m0;
        #pragma unroll
        for (int m = 0; m < 4; ++m) {
            #pragma unroll
            for (int nt = 0; nt < 4; ++nt) {
                int dnt = w * 64 + nt * 16 + lcol;
                #pragma unroll
                for (int r = 0; r < 4; ++r) {
                    int bit = m * 16 + lrow * 4 + r;
                    float x = acc[m][nt][r] + bg[nt];
                    float g = __builtin_amdgcn_rcpf(1.0f + __expf(-x));
                    float msg = g * hB[(pp * 64 + bit) * DD + dnt];
                    int on = (int)((mw >> bit) & 1ULL);
                    vs[nt] += on ? msg : 0.f;
                    vm[nt] = fmaxf(vm[nt], on ? msg : -INFINITY);
                }
            }
        }
    }

    #pragma unroll
    for (int nt = 0; nt < 4; ++nt) {
        float s = vs[nt];
        s += __shfl_xor(s, 16); s += __shfl_xor(s, 32);
        vs[nt] = s;
        float m = vm[nt];
        m = fmaxf(m, __shfl_xor(m, 16)); m = fmaxf(m, __shfl_xor(m, 32));
        vm[nt] = m;
    }
    const int g = lrow;
    float ssel = (g == 0) ? vs[0] : (g == 1) ? vs[1] : (g == 2) ? vs[2] : vs[3];
    float msel = (g == 0) ? vm[0] : (g == 1) ? vm[1] : (g == 2) ? vm[2] : vm[3];
    const int d = w * 64 + lane;
    agg_mean[(size_t)bi * DD + d] = ssel / fmaxf(cntf, 1.f);
    agg_max[(size_t)bi * DD + d] = (cntf > 0.f) ? msel : 0.f;
}

// ---------------- MFMA update MLP + residual + LN ----------------
__global__ __launch_bounds__(256) void k_upd(
    const float* __restrict__ h, const float* __restrict__ amean,
    const float* __restrict__ amax,
    const unsigned short* __restrict__ w1t,
    const float* __restrict__ ub1,
    const unsigned short* __restrict__ w2t,
    const float* __restrict__ ub2,
    const float* __restrict__ lng, const float* __restrict__ lnb,
    float* __restrict__ hout, float* __restrict__ out2)
{
    const int tid = threadIdx.x;
    const int row0 = blockIdx.x * 4;
    const int lane = tid & 63, w = tid >> 6;
    const int lcol = lane & 15, lrow = lane >> 4;

    __shared__ __align__(16) unsigned int sX32[16 * 384];
    __shared__ __align__(16) unsigned short sH16[16 * 256];
    __shared__ float sRes[4][256];
    __shared__ float sOut[4][256];

    {
        const int j = w;
        const float* hR = h + (size_t)(row0 + j) * DD;
        const float* mR = amean + (size_t)(row0 + j) * DD;
        const float* xR = amax + (size_t)(row0 + j) * DD;
        #pragma unroll
        for (int q = 0; q < 6; ++q) {
            int p = lane + q * 64;
            int k = 2 * p;
            float2 v;
            if (k < 256)      { v = *(const float2*)(hR + k); sRes[j][k] = v.x; sRes[j][k + 1] = v.y; }
            else if (k < 512)   v = *(const float2*)(mR + (k - 256));
            else                v = *(const float2*)(xR + (k - 512));
            unsigned int pk = (unsigned int)(unsigned short)f2bf(v.x) |
                              ((unsigned int)(unsigned short)f2bf(v.y) << 16);
            sX32[j * 384 + (p ^ (j << 2))] = pk;
        }
    }
    __syncthreads();

    const char* sXb = (const char*)sX32;
    const unsigned short* w1r = w1t + (size_t)(w * 64 + lcol) * 768;
    f4 a0 = {0.f, 0.f, 0.f, 0.f}, a1 = a0, a2 = a0, a3 = a0;
    #pragma unroll 4
    for (int ks = 0; ks < 24; ++ks) {
        int k0 = ks * 32 + lrow * 8;
        bs8 av = *(const bs8*)(sXb + lcol * 1536 + ((((k0 >> 3) ^ (lcol & 7))) << 4));
        bs8 b0 = *(const bs8*)(w1r + k0);
        bs8 b1 = *(const bs8*)(w1r + 16 * 768 + k0);
        bs8 b2 = *(const bs8*)(w1r + 32 * 768 + k0);
        bs8 b3 = *(const bs8*)(w1r + 48 * 768 + k0);
        a0 = __builtin_amdgcn_mfma_f32_16x16x32_bf16(av, b0, a0, 0, 0, 0);
        a1 = __builtin_amdgcn_mfma_f32_16x16x32_bf16(av, b1, a1, 0, 0, 0);
        a2 = __builtin_amdgcn_mfma_f32_16x16x32_bf16(av, b2, a2, 0, 0, 0);
        a3 = __builtin_amdgcn_mfma_f32_16x16x32_bf16(av, b3, a3, 0, 0, 0);
    }
    if (lrow == 0) {
        #pragma unroll
        for (int nt = 0; nt < 4; ++nt) {
            int d = w * 64 + nt * 16 + lcol;
            float bb = ub1[d];
            f4 A = (nt == 0) ? a0 : (nt == 1) ? a1 : (nt == 2) ? a2 : a3;
            #pragma unroll
            for (int r = 0; r < 4; ++r) {
                float hv = fmaxf(A[r] + bb, 0.f);
                sH16[r * 256 + (d ^ (r << 3))] = (unsigned short)f2bf(hv);
            }
        }
    }
    __syncthreads();

    const unsigned short* w2r = w2t + (size_t)(w * 64 + lcol) * 256;
    f4 c0 = {0.f, 0.f, 0.f, 0.f}, c1 = c0, c2 = c0, c3 = c0;
    #pragma unroll
    for (int ks = 0; ks < 8; ++ks) {
        int k0 = ks * 32 + lrow * 8;
        bs8 av = *(const bs8*)((const char*)sH16 + lcol * 512 + ((((k0 >> 3) ^ (lcol & 7))) << 4));
        bs8 b0 = *(const bs8*)(w2r + k0);
        bs8 b1 = *(const bs8*)(w2r + 16 * 256 + k0);
        bs8 b2 = *(const bs8*)(w2r + 32 * 256 + k0);
        bs8 b3 = *(const bs8*)(w2r + 48 * 256 + k0);
        c0 = __builtin_amdgcn_mfma_f32_16x16x32_bf16(av, b0, c0, 0, 0, 0);
        c1 = __builtin_amdgcn_mfma_f32_16x16x32_bf16(av, b1, c1, 0, 0, 0);
        c2 = __builtin_amdgcn_mfma_f32_16x16x32_bf16(av, b2, c2, 0, 0, 0);
        c3 = __builtin_amdgcn_mfma_f32_16x16x32_bf16(av, b3, c3, 0, 0, 0);
    }
    if (lrow == 0) {
        #pragma unroll
        for (int nt = 0; nt < 4; ++nt) {
            int d = w * 64 + nt * 16 + lcol;
            float bb = ub2[d];
            f4 C = (nt == 0) ? c0 : (nt == 1) ? c1 : (nt == 2) ? c2 : c3;
            #pragma unroll
            for (int r = 0; r < 4; ++r)
                sOut[r][d] = C[r] + bb + sRes[r][d];
        }
    }
    __syncthreads();

    float xv[4], s = 0.f;
    #pragma unroll
    for (int q = 0; q < 4; ++q) { xv[q] = sOut[w][lane + 64 * q]; s += xv[q]; }
    #pragma unroll
    for (int off = 1; off < 64; off <<= 1) s += __shfl_xor(s, off);
    const float mu = s * (1.f / DD);
    float s2 = 0.f;
    #pragma unroll
    for (int q = 0; q < 4; ++q) { float d = xv[q] - mu; s2 += d * d; }
    #pragma unroll
    for (int off = 1; off < 64; off <<= 1) s2 += __shfl_xor(s2, off);
    const float inv = rsqrtf(s2 * (1.f / DD) + 1e-5f);
    #pragma unroll
    for (int q = 0; q < 4; ++q) {
        int c = lane + 64 * q;
        float res = (xv[q] - mu) * inv * lng[c] + lnb[c];
        hout[(size_t)(row0 + w) * DD + c] = res;
        if (out2) out2[(size_t)(row0 + w) * DD + c] = res;
    }
}

// ---------------- graph embed ----------------
__global__ __launch_bounds__(256) void k_gembed(
    const float* __restrict__ nf, const float* __restrict__ h, float* __restrict__ ge)
{
    const int b = blockIdx.x, tid = threadIdx.x;
    __shared__ float sW[NN_];
    __shared__ float sRed[256];
    if (tid < NN_) {
        const float* p = nf + ((size_t)b * NN_ + tid) * 11;
        sW[tid] = p[0] * p[7];
    }
    __syncthreads();
    float part = (tid < NN_) ? sW[tid] : 0.f;
    float wsum = blockReduceSum(part, sRed);
    const float* hb = h + (size_t)b * NN_ * DD + tid;
    float a0 = 0.f, a1 = 0.f, a2 = 0.f, a3 = 0.f;
    for (int n = 0; n < 32; ++n) {
        a0 += sW[n]      * hb[(size_t)n * DD];
        a1 += sW[n + 32] * hb[(size_t)(n + 32) * DD];
        a2 += sW[n + 64] * hb[(size_t)(n + 64) * DD];
        a3 += sW[n + 96] * hb[(size_t)(n + 96) * DD];
    }
    ge[b * DD + tid] = (a0 + a1 + a2 + a3) / fmaxf(wsum, 1e-8f);
}

// ---------------- head GEMMs, all batches per weight load (lred fused in) ----------------
__global__ __launch_bounds__(256) void k_hmm(
    const float* __restrict__ ge, const float* __restrict__ gd,
    const float* __restrict__ qw, const float* __restrict__ sw1,
    const float* __restrict__ vw1,
    const float* __restrict__ lpb, const float* __restrict__ lpart,
    float* __restrict__ part)
{
    const int blk = blockIdx.x;
    const int m = blk >> 5, kseg = (blk >> 2) & 7, c4 = blk & 3;
    const int tid = threadIdx.x;
    const int d = tid & 63, ks = tid >> 6;
    const int K = (m == 1) ? 258 : 514;
    const int kc = (m == 1) ? 33 : 65;
    const int k0 = kseg * kc;
    const int klen = min(k0 + kc, K) - k0;
    __shared__ float sX[8 * 66];
    __shared__ float sP[4][8][64];
    for (int idx = tid; idx < 8 * kc; idx += 256) {
        int bb = idx / kc, kk = idx % kc, k = k0 + kk;
        float v = 0.f;
        if (k < K) {
            if (m == 1) v = (k < 256) ? ge[bb * DD + k] : gd[bb * 2 + (k - 256)];
            else if (k < 256) v = ge[bb * DD + k];
            else if (k < 512) {
                int e = k - 256;
                v = lpb[e];
                #pragma unroll
                for (int s = 0; s < 8; ++s)
                    v += lpart[(bb * 32 + s * 4 + (e >> 6)) * 64 + (e & 63)];
            } else v = gd[bb * 2 + (k - 512)];
        }
        sX[bb * 66 + kk] = v;
    }
    __syncthreads();
    const float* W = (m == 0) ? qw : (m == 1) ? sw1 : vw1;
    const int dg = c4 * 64 + d;
    float acc[8] = {0.f, 0.f, 0.f, 0.f, 0.f, 0.f, 0.f, 0.f};
    for (int kk = ks; kk < klen; kk += 4) {
        float wv = W[(size_t)(k0 + kk) * DD + dg];
        #pragma unroll
        for (int bb = 0; bb < 8; ++bb) acc[bb] += sX[bb * 66 + kk] * wv;
    }
    #pragma unroll
    for (int bb = 0; bb < 8; ++bb) sP[ks][bb][d] = acc[bb];
    __syncthreads();
    for (int idx = tid; idx < 8 * 64; idx += 256) {
        int bb = idx >> 6, dd = idx & 63;
        float sum = sP[0][bb][dd] + sP[1][bb][dd] + sP[2][bb][dd] + sP[3][bb][dd];
        part[((m * 8 + kseg) * 8 + bb) * DD + c4 * 64 + dd] = sum;
    }
}

// ---------------- head finalize ----------------
__global__ __launch_bounds__(256) void k_hfin(
    const float* __restrict__ part,
    const float* __restrict__ qb, const float* __restrict__ sb1,
    const float* __restrict__ vb1,
    const float* __restrict__ sw2, const float* __restrict__ sb2,
    const float* __restrict__ vw2, const float* __restrict__ vb2,
    float* __restrict__ query, float* __restrict__ out)
{
    const int b = blockIdx.x, tid = threadIdx.x;
    __shared__ float sRed[256];
    float q = qb[tid], s = sb1[tid], v = vb1[tid];
    #pragma unroll
    for (int kseg = 0; kseg < 8; ++kseg) {
        q += part[((0 * 8 + kseg) * 8 + b) * DD + tid];
        s += part[((1 * 8 + kseg) * 8 + b) * DD + tid];
        v += part[((2 * 8 + kseg) * 8 + b) * DD + tid];
    }
    query[b * DD + tid] = q;
    s = fmaxf(s, 0.f); v = fmaxf(v, 0.f);
    float stop = blockReduceSum(s * sw2[tid], sRed);
    float val  = blockReduceSum(v * vw2[tid], sRed);
    if (tid == 0) {
        out[b * 129 + 128] = stop + sb2[0];
        out[1032 + b] = val + vb2[0];
    }
}

// ---------------- MFMA device scores: keys = h@kw+kb, score = keys.query/16 ----------------
__global__ __launch_bounds__(256) void k_scores(
    const float* __restrict__ h, const unsigned short* __restrict__ kwt,
    const float* __restrict__ kb, const float* __restrict__ query,
    float* __restrict__ out)
{
    const int tid = threadIdx.x, blk = blockIdx.x;
    const int row0 = blk * 16, b = blk >> 3;
    const int lane = tid & 63, w = tid >> 6;
    const int lcol = lane & 15, lrow = lane >> 4;
    __shared__ float sPart[4][16];
    const float* aR = h + (size_t)(row0 + lcol) * DD;
    f4 acc[4] = {};
    #pragma unroll
    for (int ks = 0; ks < 8; ++ks) {
        int k0 = ks * 32 + lrow * 8;
        bs8 av = cvt8(aR + k0);
        #pragma unroll
        for (int nt = 0; nt < 4; ++nt) {
            bs8 bv = *(const bs8*)(kwt + (size_t)(w * 64 + nt * 16 + lcol) * 256 + k0);
            acc[nt] = __builtin_amdgcn_mfma_f32_16x16x32_bf16(av, bv, acc[nt], 0, 0, 0);
        }
    }
    float part[4] = {0.f, 0.f, 0.f, 0.f};
    #pragma unroll
    for (int nt = 0; nt < 4; ++nt) {
        int col = w * 64 + nt * 16 + lcol;
        float q = query[b * DD + col], kv = kb[col];
        #pragma unroll
        for (int r = 0; r < 4; ++r) part[r] += (acc[nt][r] + kv) * q;
    }
    #pragma unroll
    for (int r = 0; r < 4; ++r) {
        float s = part[r];
        s += __shfl_xor(s, 1); s += __shfl_xor(s, 2);
        s += __shfl_xor(s, 4); s += __shfl_xor(s, 8);
        part[r] = s;
    }
    if (lcol == 0) {
        #pragma unroll
        for (int r = 0; r < 4; ++r) sPart[w][lrow * 4 + r] = part[r];
    }
    __syncthreads();
    if (tid < 16) {
        float s = sPart[0][tid] + sPart[1][tid] + sPart[2][tid] + sPart[3][tid];
        out[b * 129 + (row0 & (NN_ - 1)) + tid] = s * 0.0625f;
    }
}

extern "C" void kernel_launch(void* const* d_in, const int* in_sizes, int n_in,
                              void* d_out, int out_size, void* d_ws, size_t ws_size,
                              hipStream_t stream) {
    (void)in_sizes; (void)n_in; (void)out_size; (void)ws_size;
    const float* nf  = (const float*)d_in[0];
    const float* ef  = (const float*)d_in[1];
    const void*  adj = d_in[2];
    const float* lc  = (const float*)d_in[3];
    const float* gd  = (const float*)d_in[4];
    const float* pnw = (const float*)d_in[5];
    const float* pnb = (const float*)d_in[6];
    const float* gw1 = (const float*)d_in[7];
    const float* gb1 = (const float*)d_in[8];
    const float* gw2 = (const float*)d_in[9];
    const float* gb2 = (const float*)d_in[10];
    const float* uw1 = (const float*)d_in[11];
    const float* ub1 = (const float*)d_in[12];
    const float* uw2 = (const float*)d_in[13];
    const float* ub2 = (const float*)d_in[14];
    const float* lng = (const float*)d_in[15];
    const float* lnb = (const float*)d_in[16];
    const float* cw  = (const float*)d_in[17];
    const float* cb  = (const float*)d_in[18];
    const float* lpw = (const float*)d_in[19];
    const float* lpb = (const float*)d_in[20];
    const float* qw  = (const float*)d_in[21];
    const float* qb  = (const float*)d_in[22];
    const float* kw  = (const float*)d_in[23];
    const float* kb  = (const float*)d_in[24];
    const float* sw1 = (const float*)d_in[25];
    const float* sb1 = (const float*)d_in[26];
    const float* sw2 = (const float*)d_in[27];
    const float* sb2 = (const float*)d_in[28];
    const float* vw1 = (const float*)d_in[29];
    const float* vb1 = (const float*)d_in[30];
    const float* vw2 = (const float*)d_in[31];
    const float* vb2 = (const float*)d_in[32];

    float* ws = (float*)d_ws;                  // d_ws is ~256 MiB (fill evidence r6)
    float* h     = ws;                         // 262144
    float* preg  = ws + 262144;                // 65536
    float* amean = ws + 327680;                // 262144
    float* amax  = ws + 589824;                // 262144
    float* ge    = ws + 851968;                // 2048
    float* query = ws + 854016;                // 2048
    float* lpart = ws + 856064;                // 16384
    float* hpart = ws + 872448;                // 49152
    int*   mode  = (int*)(ws + 921600);        // 1 (pad to 921604)
    unsigned short* uw1t = (unsigned short*)(ws + 921604);    // 589824 shorts
    unsigned short* uw2t = (unsigned short*)(ws + 1216516);   // 196608 shorts
    unsigned short* g2t  = (unsigned short*)(ws + 1314820);   // 49152 shorts
    unsigned short* g1t  = (unsigned short*)(ws + 1339396);   // 49152 shorts
    unsigned short* kwt  = (unsigned short*)(ws + 1363972);   // 65536 shorts
    float* out   = (float*)d_out;

    k_prep<<<233, 256, 0, stream>>>(uw1, uw2, gw2, gw1, kw,
                                    (const unsigned char*)adj,
                                    uw1t, uw2t, g2t, g1t, kwt, mode);
    k_nodeproj<<<BB * NN_, 256, 0, stream>>>(nf, pnw, pnb, h);
    k_lmm<<<256, 256, 0, stream>>>(lc, cw, cb, lpw, lpart);
    k_pregate<<<BB * NN_ / 16, 256, 0, stream>>>(h, g1t, gb1, preg);
    for (int i = 0; i < NG; ++i) {
        const float* gw1i = gw1 + (size_t)i * 259 * EH;
        float* out2sel = (i == NG - 1) ? (out + 1040) : (float*)nullptr;
        k_edge<<<BB * NN_, 256, 0, stream>>>(h, preg, ef, adj, mode, gw1i,
                                             g2t + (size_t)i * 16384,
                                             gb2 + i * DD, amean, amax);
        k_upd<<<BB * NN_ / 4, 256, 0, stream>>>(h, amean, amax,
                                                uw1t + (size_t)i * 196608, ub1 + i * DD,
                                                uw2t + (size_t)i * 65536, ub2 + i * DD,
                                                lng + i * DD, lnb + i * DD, h, out2sel);
        if (i < NG - 1)
            k_pregate<<<BB * NN_ / 16, 256, 0, stream>>>(h, g1t + (size_t)(i + 1) * 16384,
                                                         gb1 + (i + 1) * EH, preg);
    }
    k_gembed<<<BB, 256, 0, stream>>>(nf, h, ge);
    k_hmm<<<96, 256, 0, stream>>>(ge, gd, qw, sw1, vw1, lpb, lpart, hpart);
    k_hfin<<<BB, 256, 0, stream>>>(hpart, qb, sb1, vb1, sw2, sb2, vw2, vb2, query, out);
    k_scores<<<BB * NN_ / 16, 256, 0, stream>>>(h, kwt, kb, query, out);
}

// Round 8
// 184.124 us; speedup vs baseline: 3.1457x; 1.0796x over previous
//
#include <hip/hip_runtime.h>
#include <hip/hip_bf16.h>
#include <math.h>

// Problem constants
#define BB 8
#define NN_ 128
#define DD 256
#define LL 64
#define EH 64
#define NG 3

typedef __attribute__((ext_vector_type(8))) short bs8;   // 8 bf16 (4 VGPR)
typedef __attribute__((ext_vector_type(4))) float f4;    // 4 f32

__device__ __forceinline__ short f2bf(float f) {
    __hip_bfloat16 h = __float2bfloat16(f);
    return *reinterpret_cast<short*>(&h);
}

__device__ __forceinline__ bs8 cvt8(const float* __restrict__ p) {
    bs8 r;
    #pragma unroll
    for (int i = 0; i < 8; ++i) r[i] = f2bf(p[i]);
    return r;
}

__device__ __forceinline__ float blockReduceSum(float v, float* sRed) {
    int tid = threadIdx.x;
    __syncthreads();
    sRed[tid] = v;
    __syncthreads();
    for (int s = 128; s > 0; s >>= 1) {
        if (tid < s) sRed[tid] += sRed[tid + s];
        __syncthreads();
    }
    return sRed[0];
}

// ---------------- unified prep: weight transposes + adj probe + layer-cost GEMM ----------------
// blocks 0..143 uw1, 144..191 uw2, 192..203 gw2, 204..215 gw1[:256], 216..231 kw,
// 232 adj-detect, 233..488 layer-cost conv+split-k GEMM
__global__ __launch_bounds__(256) void k_prep(
    const float* __restrict__ uw1, const float* __restrict__ uw2,
    const float* __restrict__ gw2, const float* __restrict__ gw1,
    const float* __restrict__ kw, const unsigned char* __restrict__ adj,
    const float* __restrict__ lc, const float* __restrict__ cw,
    const float* __restrict__ cb, const float* __restrict__ lpw,
    unsigned short* __restrict__ w1t, unsigned short* __restrict__ w2t,
    unsigned short* __restrict__ g2t, unsigned short* __restrict__ g1t,
    unsigned short* __restrict__ kwt, int* __restrict__ mode,
    float* __restrict__ lpart)
{
    const int blk = blockIdx.x, tid = threadIdx.x;
    if (blk == 232) {   // adj dtype probe: 0 = bool8, 1 = int32, 2 = float32
        __shared__ int sOff, sBig;
        if (tid == 0) { sOff = 0; sBig = 0; }
        __syncthreads();
        int off = 0, big = 0;
        #pragma unroll
        for (int k = 0; k < 4; ++k) {
            unsigned char v = adj[tid * 4 + k];
            if (v > 1) big = 1;
            if (k != 0 && v != 0) off = 1;
        }
        if (off) atomicOr(&sOff, 1);
        if (big) atomicOr(&sBig, 1);
        __syncthreads();
        if (tid == 0) mode[0] = sBig ? 2 : (sOff ? 0 : 1);
        return;
    }
    if (blk > 232) {    // layer-cost: conv + split-k GEMM -> lpart
        const int lb = blk - 233;
        const int b = lb >> 5, kseg = (lb >> 2) & 7, c4 = lb & 3;
        const int d = tid & 63, ss = tid >> 6;
        __shared__ float sC[LL];
        __shared__ float sV[124];
        __shared__ float sP[4][64];
        if (tid < LL) sC[tid] = lc[b * LL + tid];
        __syncthreads();
        if (tid < 124) {
            int idx = kseg * 124 + tid;
            int c = idx / 31, t = idx - c * 31;
            float a = cb[c];
            #pragma unroll
            for (int k = 0; k < 4; ++k) a += sC[2 * t + k] * cw[c * 4 + k];
            sV[tid] = fmaxf(a, 0.f);
        }
        __syncthreads();
        float acc = 0.f;
        for (int k = ss; k < 124; k += 4)
            acc += sV[k] * lpw[(size_t)(kseg * 124 + k) * DD + c4 * 64 + d];
        sP[ss][d] = acc;
        __syncthreads();
        if (ss == 0)
            lpart[(b * 32 + kseg * 4 + c4) * 64 + d] = sP[0][d] + sP[1][d] + sP[2][d] + sP[3][d];
        return;
    }
    // weight transposes
    const float* src; unsigned short* dst; int K, kt, dt, srcw = 256;
    if (blk < 144)      { int l = blk / 48, t = blk % 48; kt = t >> 2; dt = t & 3;
                          src = uw1 + (size_t)l * 196608; dst = w1t + (size_t)l * 196608; K = 768; }
    else if (blk < 192) { int x = blk - 144, l = x / 16, t = x % 16; kt = t >> 2; dt = t & 3;
                          src = uw2 + (size_t)l * 65536; dst = w2t + (size_t)l * 65536; K = 256; }
    else if (blk < 204) { int x = blk - 192, l = x >> 2; kt = 0; dt = x & 3;
                          src = gw2 + (size_t)l * 16384; dst = g2t + (size_t)l * 16384; K = 64; }
    else if (blk < 216) { int x = blk - 204, l = x >> 2; kt = x & 3; dt = 0; srcw = 64;
                          src = gw1 + (size_t)l * 16576; dst = g1t + (size_t)l * 16384; K = 256; }
    else                { int x = blk - 216; kt = x >> 2; dt = x & 3;
                          src = kw; dst = kwt; K = 256; }
    __shared__ float sT[64][65];
    #pragma unroll
    for (int q = 0; q < 16; ++q) {
        int idx = q * 256 + tid, kk = idx >> 6, dd = idx & 63;
        sT[kk][dd] = src[(size_t)(kt * 64 + kk) * srcw + dt * 64 + dd];
    }
    __syncthreads();
    const int d = tid >> 2, kc = (tid & 3) * 16;
    unsigned short* drow = dst + (size_t)(dt * 64 + d) * K + kt * 64 + kc;
    #pragma unroll
    for (int i = 0; i < 16; ++i) drow[i] = (unsigned short)f2bf(sT[kc + i][d]);
}

// ---------------- node projection + layer-0 pregate (16 rows/block, grid 64) ----------------
__global__ __launch_bounds__(256) void k_npp(
    const float* __restrict__ nf, const float* __restrict__ pnw,
    const float* __restrict__ pnb,
    const unsigned short* __restrict__ g1t, const float* __restrict__ gb1,
    float* __restrict__ h, float* __restrict__ preg)
{
    const int tid = threadIdx.x, blk = blockIdx.x;
    const int row0 = blk * 16;
    const int lane = tid & 63, w = tid >> 6;
    const int lcol = lane & 15, lrow = lane >> 4;
    __shared__ float sF[16][12];
    __shared__ float sH[16][260];    // +4 pad: rows land on distinct banks for MFMA A reads
    if (tid < 176) sF[tid / 11][tid % 11] = nf[(size_t)(row0 + tid / 11) * 11 + tid % 11];
    __syncthreads();
    float acc[16];
    {
        float bb = pnb[tid];
        #pragma unroll
        for (int rr = 0; rr < 16; ++rr) acc[rr] = bb;
    }
    #pragma unroll
    for (int f = 0; f < 11; ++f) {
        float wf = pnw[f * DD + tid];
        #pragma unroll
        for (int rr = 0; rr < 16; ++rr) acc[rr] += sF[rr][f] * wf;
    }
    #pragma unroll
    for (int rr = 0; rr < 16; ++rr) {
        sH[rr][tid] = acc[rr];
        h[(size_t)(row0 + rr) * DD + tid] = acc[rr];
    }
    __syncthreads();
    // pregate layer 0
    const unsigned short* bR = g1t + (size_t)(w * 16 + lcol) * 256;
    f4 a2 = {0.f, 0.f, 0.f, 0.f};
    #pragma unroll
    for (int ks = 0; ks < 8; ++ks) {
        int k0 = ks * 32 + lrow * 8;
        bs8 av = cvt8(&sH[lcol][k0]);
        bs8 bv = *(const bs8*)(bR + k0);
        a2 = __builtin_amdgcn_mfma_f32_16x16x32_bf16(av, bv, a2, 0, 0, 0);
    }
    const float gb = gb1[w * 16 + lcol];
    #pragma unroll
    for (int r = 0; r < 4; ++r)
        preg[(size_t)(row0 + lrow * 4 + r) * EH + w * 16 + lcol] = a2[r] + gb;
}

// ---------------- fused edge-gate (MFMA) + masked aggregation ----------------
__global__ __launch_bounds__(256) void k_edge(
    const float* __restrict__ h, const float* __restrict__ preg,
    const float* __restrict__ edge, const void* __restrict__ adj,
    const int* __restrict__ mode,
    const float* __restrict__ gw1,
    const unsigned short* __restrict__ g2t,
    const float* __restrict__ gb2,
    float* __restrict__ agg_mean, float* __restrict__ agg_max)
{
    const int tid = threadIdx.x;
    const int bi = blockIdx.x;
    const int b = bi >> 7;
    const int lane = tid & 63, w = tid >> 6;
    const int lrow = lane >> 4, lcol = lane & 15;
    const int md = mode[0];

    __shared__ __align__(16) unsigned int sHid[4096];
    __shared__ float sWe[192];
    __shared__ float sE[384];
    __shared__ unsigned long long sMask[2];

    if (tid < 192) sWe[tid] = gw1[16384 + tid];
    const float* eB = edge + (size_t)bi * 384;
    for (int idx = tid; idx < 384; idx += 256) sE[idx] = eB[idx];
    if (tid < 128) {
        int mv;
        if (md == 1)      mv = ((const int*)adj)[(size_t)bi * NN_ + tid] != 0;
        else if (md == 2) mv = ((const float*)adj)[(size_t)bi * NN_ + tid] != 0.f;
        else              mv = ((const unsigned char*)adj)[(size_t)bi * NN_ + tid] != 0;
        unsigned long long bal = __ballot(mv);
        if ((tid & 63) == 0) sMask[tid >> 6] = bal;
    }
    __syncthreads();

    const float* pB = preg + (size_t)b * NN_ * EH;
    #pragma unroll
    for (int q = 0; q < 16; ++q) {
        int idx = q * 256 + tid;
        int j = idx >> 5, p = idx & 31;
        float2 pv = *(const float2*)(pB + j * EH + 2 * p);
        float e0 = sE[j * 3], e1 = sE[j * 3 + 1], e2 = sE[j * 3 + 2];
        int t0 = 2 * p, t1 = t0 + 1;
        float v0 = fmaxf(pv.x + e0 * sWe[t0] + e1 * sWe[64 + t0] + e2 * sWe[128 + t0], 0.f);
        float v1 = fmaxf(pv.y + e0 * sWe[t1] + e1 * sWe[64 + t1] + e2 * sWe[128 + t1], 0.f);
        unsigned int pk = (unsigned int)(unsigned short)f2bf(v0) |
                          ((unsigned int)(unsigned short)f2bf(v1) << 16);
        sHid[j * 32 + (p ^ ((j & 7) << 2))] = pk;
    }
    __syncthreads();

    const unsigned long long m0 = sMask[0], m1 = sMask[1];
    const float cntf = (float)(__popcll(m0) + __popcll(m1));

    bs8 bfr[4][2];
    float bg[4];
    #pragma unroll
    for (int nt = 0; nt < 4; ++nt) {
        int d = w * 64 + nt * 16 + lcol;
        bg[nt] = gb2[d];
        #pragma unroll
        for (int ks = 0; ks < 2; ++ks) {
            int k0 = ks * 32 + lrow * 8;
            bfr[nt][ks] = *(const bs8*)(g2t + (size_t)d * 64 + k0);
        }
    }

    const float* hB = h + (size_t)b * NN_ * DD;
    float vs[4] = {0.f, 0.f, 0.f, 0.f};
    float vm[4] = {-INFINITY, -INFINITY, -INFINITY, -INFINITY};

    #pragma unroll
    for (int pp = 0; pp < 2; ++pp) {
        f4 acc[4][4] = {};
        #pragma unroll
        for (int ks = 0; ks < 2; ++ks) {
            bs8 afr[4];
            #pragma unroll
            for (int m = 0; m < 4; ++m) {
                int j = pp * 64 + m * 16 + lcol;
                int k0 = ks * 32 + lrow * 8;
                afr[m] = *(const bs8*)(sHid + (j * 32 + ((k0 >> 1) ^ ((j & 7) << 2))));
            }
            #pragma unroll
            for (int m = 0; m < 4; ++m)
                #pragma unroll
                for (int nt = 0; nt < 4; ++nt)
                    acc[m][nt] = __builtin_amdgcn_mfma_f32_16x16x32_bf16(
                        afr[m], bfr[nt][ks], acc[m][nt], 0, 0, 0);
        }
        const unsigned long long mw = pp ? m1 : m0;
        #pragma unroll
        for (int m = 0; m < 4; ++m) {
            #pragma unroll
            for (int nt = 0; nt < 4; ++nt) {
                int dnt = w * 64 + nt * 16 + lcol;
                #pragma unroll
                for (int r = 0; r < 4; ++r) {
                    int bit = m * 16 + lrow * 4 + r;
                    float x = acc[m][nt][r] + bg[nt];
                    float g = __builtin_amdgcn_rcpf(1.0f + __expf(-x));
                    float msg = g * hB[(pp * 64 + bit) * DD + dnt];
                    int on = (int)((mw >> bit) & 1ULL);
                    vs[nt] += on ? msg : 0.f;
                    vm[nt] = fmaxf(vm[nt], on ? msg : -INFINITY);
                }
            }
        }
    }

    #pragma unroll
    for (int nt = 0; nt < 4; ++nt) {
        float s = vs[nt];
        s += __shfl_xor(s, 16); s += __shfl_xor(s, 32);
        vs[nt] = s;
        float m = vm[nt];
        m = fmaxf(m, __shfl_xor(m, 16)); m = fmaxf(m, __shfl_xor(m, 32));
        vm[nt] = m;
    }
    const int g = lrow;
    float ssel = (g == 0) ? vs[0] : (g == 1) ? vs[1] : (g == 2) ? vs[2] : vs[3];
    float msel = (g == 0) ? vm[0] : (g == 1) ? vm[1] : (g == 2) ? vm[2] : vm[3];
    const int d = w * 64 + lane;
    agg_mean[(size_t)bi * DD + d] = ssel / fmaxf(cntf, 1.f);
    agg_max[(size_t)bi * DD + d] = (cntf > 0.f) ? msel : 0.f;
}

// ---------------- MFMA update MLP + residual + LN + next-layer pregate ----------------
__global__ __launch_bounds__(256) void k_updp(
    const float* __restrict__ h, const float* __restrict__ amean,
    const float* __restrict__ amax,
    const unsigned short* __restrict__ w1t,
    const float* __restrict__ ub1,
    const unsigned short* __restrict__ w2t,
    const float* __restrict__ ub2,
    const float* __restrict__ lng, const float* __restrict__ lnb,
    float* __restrict__ hout, float* __restrict__ out2,
    const unsigned short* __restrict__ g1tn, const float* __restrict__ gb1n,
    float* __restrict__ preg)
{
    const int tid = threadIdx.x;
    const int row0 = blockIdx.x * 4;
    const int lane = tid & 63, w = tid >> 6;
    const int lcol = lane & 15, lrow = lane >> 4;

    __shared__ __align__(16) unsigned int sX32[16 * 384];
    __shared__ __align__(16) unsigned short sH16[16 * 256];
    __shared__ float sRes[4][256];
    __shared__ float sOut[4][260];   // +4 pad for pregate A reads

    {
        const int j = w;
        const float* hR = h + (size_t)(row0 + j) * DD;
        const float* mR = amean + (size_t)(row0 + j) * DD;
        const float* xR = amax + (size_t)(row0 + j) * DD;
        #pragma unroll
        for (int q = 0; q < 6; ++q) {
            int p = lane + q * 64;
            int k = 2 * p;
            float2 v;
            if (k < 256)      { v = *(const float2*)(hR + k); sRes[j][k] = v.x; sRes[j][k + 1] = v.y; }
            else if (k < 512)   v = *(const float2*)(mR + (k - 256));
            else                v = *(const float2*)(xR + (k - 512));
            unsigned int pk = (unsigned int)(unsigned short)f2bf(v.x) |
                              ((unsigned int)(unsigned short)f2bf(v.y) << 16);
            sX32[j * 384 + (p ^ (j << 2))] = pk;
        }
    }
    __syncthreads();

    const char* sXb = (const char*)sX32;
    const unsigned short* w1r = w1t + (size_t)(w * 64 + lcol) * 768;
    f4 a0 = {0.f, 0.f, 0.f, 0.f}, a1 = a0, a2 = a0, a3 = a0;
    #pragma unroll 4
    for (int ks = 0; ks < 24; ++ks) {
        int k0 = ks * 32 + lrow * 8;
        bs8 av = *(const bs8*)(sXb + lcol * 1536 + ((((k0 >> 3) ^ (lcol & 7))) << 4));
        bs8 b0 = *(const bs8*)(w1r + k0);
        bs8 b1 = *(const bs8*)(w1r + 16 * 768 + k0);
        bs8 b2 = *(const bs8*)(w1r + 32 * 768 + k0);
        bs8 b3 = *(const bs8*)(w1r + 48 * 768 + k0);
        a0 = __builtin_amdgcn_mfma_f32_16x16x32_bf16(av, b0, a0, 0, 0, 0);
        a1 = __builtin_amdgcn_mfma_f32_16x16x32_bf16(av, b1, a1, 0, 0, 0);
        a2 = __builtin_amdgcn_mfma_f32_16x16x32_bf16(av, b2, a2, 0, 0, 0);
        a3 = __builtin_amdgcn_mfma_f32_16x16x32_bf16(av, b3, a3, 0, 0, 0);
    }
    if (lrow == 0) {
        #pragma unroll
        for (int nt = 0; nt < 4; ++nt) {
            int d = w * 64 + nt * 16 + lcol;
            float bb = ub1[d];
            f4 A = (nt == 0) ? a0 : (nt == 1) ? a1 : (nt == 2) ? a2 : a3;
            #pragma unroll
            for (int r = 0; r < 4; ++r) {
                float hv = fmaxf(A[r] + bb, 0.f);
                sH16[r * 256 + (d ^ (r << 3))] = (unsigned short)f2bf(hv);
            }
        }
    }
    __syncthreads();

    const unsigned short* w2r = w2t + (size_t)(w * 64 + lcol) * 256;
    f4 c0 = {0.f, 0.f, 0.f, 0.f}, c1 = c0, c2 = c0, c3 = c0;
    #pragma unroll
    for (int ks = 0; ks < 8; ++ks) {
        int k0 = ks * 32 + lrow * 8;
        bs8 av = *(const bs8*)((const char*)sH16 + lcol * 512 + ((((k0 >> 3) ^ (lcol & 7))) << 4));
        bs8 b0 = *(const bs8*)(w2r + k0);
        bs8 b1 = *(const bs8*)(w2r + 16 * 256 + k0);
        bs8 b2 = *(const bs8*)(w2r + 32 * 256 + k0);
        bs8 b3 = *(const bs8*)(w2r + 48 * 256 + k0);
        c0 = __builtin_amdgcn_mfma_f32_16x16x32_bf16(av, b0, c0, 0, 0, 0);
        c1 = __builtin_amdgcn_mfma_f32_16x16x32_bf16(av, b1, c1, 0, 0, 0);
        c2 = __builtin_amdgcn_mfma_f32_16x16x32_bf16(av, b2, c2, 0, 0, 0);
        c3 = __builtin_amdgcn_mfma_f32_16x16x32_bf16(av, b3, c3, 0, 0, 0);
    }
    if (lrow == 0) {
        #pragma unroll
        for (int nt = 0; nt < 4; ++nt) {
            int d = w * 64 + nt * 16 + lcol;
            float bb = ub2[d];
            f4 C = (nt == 0) ? c0 : (nt == 1) ? c1 : (nt == 2) ? c2 : c3;
            #pragma unroll
            for (int r = 0; r < 4; ++r)
                sOut[r][d] = C[r] + bb + sRes[r][d];
        }
    }
    __syncthreads();

    // LN: wave w handles row w (two-pass, shfl-only)
    float xv[4], s = 0.f;
    #pragma unroll
    for (int q = 0; q < 4; ++q) { xv[q] = sOut[w][lane + 64 * q]; s += xv[q]; }
    #pragma unroll
    for (int off = 1; off < 64; off <<= 1) s += __shfl_xor(s, off);
    const float mu = s * (1.f / DD);
    float s2 = 0.f;
    #pragma unroll
    for (int q = 0; q < 4; ++q) { float d = xv[q] - mu; s2 += d * d; }
    #pragma unroll
    for (int off = 1; off < 64; off <<= 1) s2 += __shfl_xor(s2, off);
    const float inv = rsqrtf(s2 * (1.f / DD) + 1e-5f);
    #pragma unroll
    for (int q = 0; q < 4; ++q) {
        int c = lane + 64 * q;
        float res = (xv[q] - mu) * inv * lng[c] + lnb[c];
        hout[(size_t)(row0 + w) * DD + c] = res;
        if (out2) out2[(size_t)(row0 + w) * DD + c] = res;
        sOut[w][c] = res;                    // post-LN into LDS for fused pregate
    }
    if (g1tn) {
        __syncthreads();
        const unsigned short* bR = g1tn + (size_t)(w * 16 + lcol) * 256;
        f4 p = {0.f, 0.f, 0.f, 0.f};
        #pragma unroll
        for (int ks = 0; ks < 8; ++ks) {
            int k0 = ks * 32 + lrow * 8;
            bs8 av = cvt8(&sOut[lcol & 3][k0]);   // A rows 4-15 duplicate 0-3 (unstored)
            bs8 bv = *(const bs8*)(bR + k0);
            p = __builtin_amdgcn_mfma_f32_16x16x32_bf16(av, bv, p, 0, 0, 0);
        }
        if (lrow == 0) {
            const float gb = gb1n[w * 16 + lcol];
            #pragma unroll
            for (int r = 0; r < 4; ++r)
                preg[(size_t)(row0 + r) * EH + w * 16 + lcol] = p[r] + gb;
        }
    }
}

// ---------------- graph embed ----------------
__global__ __launch_bounds__(256) void k_gembed(
    const float* __restrict__ nf, const float* __restrict__ h, float* __restrict__ ge)
{
    const int b = blockIdx.x, tid = threadIdx.x;
    __shared__ float sW[NN_];
    __shared__ float sRed[256];
    if (tid < NN_) {
        const float* p = nf + ((size_t)b * NN_ + tid) * 11;
        sW[tid] = p[0] * p[7];
    }
    __syncthreads();
    float part = (tid < NN_) ? sW[tid] : 0.f;
    float wsum = blockReduceSum(part, sRed);
    const float* hb = h + (size_t)b * NN_ * DD + tid;
    float a0 = 0.f, a1 = 0.f, a2 = 0.f, a3 = 0.f;
    for (int n = 0; n < 32; ++n) {
        a0 += sW[n]      * hb[(size_t)n * DD];
        a1 += sW[n + 32] * hb[(size_t)(n + 32) * DD];
        a2 += sW[n + 64] * hb[(size_t)(n + 64) * DD];
        a3 += sW[n + 96] * hb[(size_t)(n + 96) * DD];
    }
    ge[b * DD + tid] = (a0 + a1 + a2 + a3) / fmaxf(wsum, 1e-8f);
}

// ---------------- head GEMMs, all batches per weight load (le reconstructed) ----------------
__global__ __launch_bounds__(256) void k_hmm(
    const float* __restrict__ ge, const float* __restrict__ gd,
    const float* __restrict__ qw, const float* __restrict__ sw1,
    const float* __restrict__ vw1,
    const float* __restrict__ lpb, const float* __restrict__ lpart,
    float* __restrict__ part)
{
    const int blk = blockIdx.x;
    const int m = blk >> 5, kseg = (blk >> 2) & 7, c4 = blk & 3;
    const int tid = threadIdx.x;
    const int d = tid & 63, ks = tid >> 6;
    const int K = (m == 1) ? 258 : 514;
    const int kc = (m == 1) ? 33 : 65;
    const int k0 = kseg * kc;
    const int klen = min(k0 + kc, K) - k0;
    __shared__ float sX[8 * 66];
    __shared__ float sP[4][8][64];
    for (int idx = tid; idx < 8 * kc; idx += 256) {
        int bb = idx / kc, kk = idx % kc, k = k0 + kk;
        float v = 0.f;
        if (k < K) {
            if (m == 1) v = (k < 256) ? ge[bb * DD + k] : gd[bb * 2 + (k - 256)];
            else if (k < 256) v = ge[bb * DD + k];
            else if (k < 512) {
                int e = k - 256;
                v = lpb[e];
                #pragma unroll
                for (int s = 0; s < 8; ++s)
                    v += lpart[(bb * 32 + s * 4 + (e >> 6)) * 64 + (e & 63)];
            } else v = gd[bb * 2 + (k - 512)];
        }
        sX[bb * 66 + kk] = v;
    }
    __syncthreads();
    const float* W = (m == 0) ? qw : (m == 1) ? sw1 : vw1;
    const int dg = c4 * 64 + d;
    float acc[8] = {0.f, 0.f, 0.f, 0.f, 0.f, 0.f, 0.f, 0.f};
    for (int kk = ks; kk < klen; kk += 4) {
        float wv = W[(size_t)(k0 + kk) * DD + dg];
        #pragma unroll
        for (int bb = 0; bb < 8; ++bb) acc[bb] += sX[bb * 66 + kk] * wv;
    }
    #pragma unroll
    for (int bb = 0; bb < 8; ++bb) sP[ks][bb][d] = acc[bb];
    __syncthreads();
    for (int idx = tid; idx < 8 * 64; idx += 256) {
        int bb = idx >> 6, dd = idx & 63;
        float sum = sP[0][bb][dd] + sP[1][bb][dd] + sP[2][bb][dd] + sP[3][bb][dd];
        part[((m * 8 + kseg) * 8 + bb) * DD + c4 * 64 + dd] = sum;
    }
}

// ---------------- MFMA device scores + query reduce + stop/value (fused tail) ----------------
__global__ __launch_bounds__(256) void k_scr(
    const float* __restrict__ h, const unsigned short* __restrict__ kwt,
    const float* __restrict__ kb, const float* __restrict__ hpart,
    const float* __restrict__ qb,
    const float* __restrict__ sb1, const float* __restrict__ vb1,
    const float* __restrict__ sw2, const float* __restrict__ sb2,
    const float* __restrict__ vw2, const float* __restrict__ vb2,
    float* __restrict__ out)
{
    const int tid = threadIdx.x, blk = blockIdx.x;
    const int row0 = blk * 16, b = blk >> 3, chunk = blk & 7;
    const int lane = tid & 63, w = tid >> 6;
    const int lcol = lane & 15, lrow = lane >> 4;
    __shared__ float sQ[256];
    __shared__ float sPart[4][16];
    __shared__ float sRed[256];
    // query for this batch (replicated reduce; removes k_hfin dependency)
    {
        float qv = qb[tid];
        #pragma unroll
        for (int kseg = 0; kseg < 8; ++kseg)
            qv += hpart[(size_t)(kseg * 8 + b) * DD + tid];
        sQ[tid] = qv;
    }
    __syncthreads();
    const float* aR = h + (size_t)(row0 + lcol) * DD;
    f4 acc[4] = {};
    #pragma unroll
    for (int ks = 0; ks < 8; ++ks) {
        int k0 = ks * 32 + lrow * 8;
        bs8 av = cvt8(aR + k0);
        #pragma unroll
        for (int nt = 0; nt < 4; ++nt) {
            bs8 bv = *(const bs8*)(kwt + (size_t)(w * 64 + nt * 16 + lcol) * 256 + k0);
            acc[nt] = __builtin_amdgcn_mfma_f32_16x16x32_bf16(av, bv, acc[nt], 0, 0, 0);
        }
    }
    float part[4] = {0.f, 0.f, 0.f, 0.f};
    #pragma unroll
    for (int nt = 0; nt < 4; ++nt) {
        int col = w * 64 + nt * 16 + lcol;
        float q = sQ[col], kv = kb[col];
        #pragma unroll
        for (int r = 0; r < 4; ++r) part[r] += (acc[nt][r] + kv) * q;
    }
    #pragma unroll
    for (int r = 0; r < 4; ++r) {
        float s = part[r];
        s += __shfl_xor(s, 1); s += __shfl_xor(s, 2);
        s += __shfl_xor(s, 4); s += __shfl_xor(s, 8);
        part[r] = s;
    }
    if (lcol == 0) {
        #pragma unroll
        for (int r = 0; r < 4; ++r) sPart[w][lrow * 4 + r] = part[r];
    }
    __syncthreads();
    if (tid < 16) {
        float s = sPart[0][tid] + sPart[1][tid] + sPart[2][tid] + sPart[3][tid];
        out[b * 129 + (row0 & (NN_ - 1)) + tid] = s * 0.0625f;
    }
    // stop/value heads: one block per batch (chunk 0)
    if (chunk == 0) {
        float s = sb1[tid], v = vb1[tid];
        #pragma unroll
        for (int kseg = 0; kseg < 8; ++kseg) {
            s += hpart[(size_t)((8 + kseg) * 8 + b) * DD + tid];
            v += hpart[(size_t)((16 + kseg) * 8 + b) * DD + tid];
        }
        s = fmaxf(s, 0.f); v = fmaxf(v, 0.f);
        float stop = blockReduceSum(s * sw2[tid], sRed);
        float val  = blockReduceSum(v * vw2[tid], sRed);
        if (tid == 0) {
            out[b * 129 + 128] = stop + sb2[0];
            out[1032 + b] = val + vb2[0];
        }
    }
}

extern "C" void kernel_launch(void* const* d_in, const int* in_sizes, int n_in,
                              void* d_out, int out_size, void* d_ws, size_t ws_size,
                              hipStream_t stream) {
    (void)in_sizes; (void)n_in; (void)out_size; (void)ws_size;
    const float* nf  = (const float*)d_in[0];
    const float* ef  = (const float*)d_in[1];
    const void*  adj = d_in[2];
    const float* lc  = (const float*)d_in[3];
    const float* gd  = (const float*)d_in[4];
    const float* pnw = (const float*)d_in[5];
    const float* pnb = (const float*)d_in[6];
    const float* gw1 = (const float*)d_in[7];
    const float* gb1 = (const float*)d_in[8];
    const float* gw2 = (const float*)d_in[9];
    const float* gb2 = (const float*)d_in[10];
    const float* uw1 = (const float*)d_in[11];
    const float* ub1 = (const float*)d_in[12];
    const float* uw2 = (const float*)d_in[13];
    const float* ub2 = (const float*)d_in[14];
    const float* lng = (const float*)d_in[15];
    const float* lnb = (const float*)d_in[16];
    const float* cw  = (const float*)d_in[17];
    const float* cb  = (const float*)d_in[18];
    const float* lpw = (const float*)d_in[19];
    const float* lpb = (const float*)d_in[20];
    const float* qw  = (const float*)d_in[21];
    const float* qb  = (const float*)d_in[22];
    const float* kw  = (const float*)d_in[23];
    const float* kb  = (const float*)d_in[24];
    const float* sw1 = (const float*)d_in[25];
    const float* sb1 = (const float*)d_in[26];
    const float* sw2 = (const float*)d_in[27];
    const float* sb2 = (const float*)d_in[28];
    const float* vw1 = (const float*)d_in[29];
    const float* vb1 = (const float*)d_in[30];
    const float* vw2 = (const float*)d_in[31];
    const float* vb2 = (const float*)d_in[32];

    float* ws = (float*)d_ws;
    float* h     = ws;                         // 262144
    float* preg  = ws + 262144;                // 65536
    float* amean = ws + 327680;                // 262144
    float* amax  = ws + 589824;                // 262144
    float* ge    = ws + 851968;                // 2048
    float* lpart = ws + 856064;                // 16384
    float* hpart = ws + 872448;                // 49152
    int*   mode  = (int*)(ws + 921600);        // 1 (pad to 921604)
    unsigned short* uw1t = (unsigned short*)(ws + 921604);    // 589824 shorts
    unsigned short* uw2t = (unsigned short*)(ws + 1216516);   // 196608 shorts
    unsigned short* g2t  = (unsigned short*)(ws + 1314820);   // 49152 shorts
    unsigned short* g1t  = (unsigned short*)(ws + 1339396);   // 49152 shorts
    unsigned short* kwt  = (unsigned short*)(ws + 1363972);   // 65536 shorts
    float* out   = (float*)d_out;

    k_prep<<<489, 256, 0, stream>>>(uw1, uw2, gw2, gw1, kw,
                                    (const unsigned char*)adj,
                                    lc, cw, cb, lpw,
                                    uw1t, uw2t, g2t, g1t, kwt, mode, lpart);
    k_npp<<<BB * NN_ / 16, 256, 0, stream>>>(nf, pnw, pnb, g1t, gb1, h, preg);
    for (int i = 0; i < NG; ++i) {
        const float* gw1i = gw1 + (size_t)i * 259 * EH;
        float* out2sel = (i == NG - 1) ? (out + 1040) : (float*)nullptr;
        const unsigned short* g1tn = (i < NG - 1) ? (g1t + (size_t)(i + 1) * 16384)
                                                  : (const unsigned short*)nullptr;
        const float* gb1n = (i < NG - 1) ? (gb1 + (i + 1) * EH) : (const float*)nullptr;
        k_edge<<<BB * NN_, 256, 0, stream>>>(h, preg, ef, adj, mode, gw1i,
                                             g2t + (size_t)i * 16384,
                                             gb2 + i * DD, amean, amax);
        k_updp<<<BB * NN_ / 4, 256, 0, stream>>>(h, amean, amax,
                                                 uw1t + (size_t)i * 196608, ub1 + i * DD,
                                                 uw2t + (size_t)i * 65536, ub2 + i * DD,
                                                 lng + i * DD, lnb + i * DD, h, out2sel,
                                                 g1tn, gb1n, preg);
    }
    k_gembed<<<BB, 256, 0, stream>>>(nf, h, ge);
    k_hmm<<<96, 256, 0, stream>>>(ge, gd, qw, sw1, vw1, lpb, lpart, hpart);
    k_scr<<<BB * NN_ / 16, 256, 0, stream>>>(h, kwt, kb, hpart, qb, sb1, vb1,
                                             sw2, sb2, vw2, vb2, out);
}